// Round 9
// baseline (710.032 us; speedup 1.0000x reference)
//
#include <hip/hip_runtime.h>
#include <hip/hip_bf16.h>
#include <math.h>

// B=8 N=196 D=512 M=20 K=77 H=8 hd=64, keep=51.  All inputs/outputs fp32.
// out1 = Qs/nrm (B,N,D,M) 16,056,320 fl; out2 = attn_weights (B,K,N) 120,736 fl
// Workspace layout: see kernel_launch. Dead-region reuse:
//   wsum -> qws (@1048576, dead after k3), Sv -> kmat (@1088000, dead after k3),
//   Qp -> OWT (@786432, 156800 fl needed <= 262144, dead after k6).
//
// R15 (from R14: k7 303us, arch 64 + 16..32 AGPR rule verified, Occ 41% at
// 2 blk/CU -> still latency-bound; k6 only 77 blocks on 256 CUs):
//  1. k7: 5 uniform chunks of MT=1 (16 rows each). Struct ~43KB -> 3 blk/CU
//     -> 24 waves/CU -> cap ~85; live ~64 arch + 16 AGPR = 80, no spill.
//     Qp = 5 partials/bn; k8 sums 5. Cost: w1 re-read x5/3 (L2 has headroom).
//  2. k6: 4 rows/block -> 154 blocks (mirrors k2's verified split; AO bitwise
//     identical - same per-row reduction order).

typedef unsigned int uint;
typedef _Float16 f16x8 __attribute__((ext_vector_type(8)));
typedef float f32x4 __attribute__((ext_vector_type(4)));

#define DI __device__ __forceinline__

DI float wsumf(float v){ for(int o=32;o>0;o>>=1) v += __shfl_xor(v,o,64); return v; }
DI int   wsumi(int v){ for(int o=32;o>0;o>>=1) v += __shfl_xor(v,o,64); return v; }
DI float wmaxf(float v){ for(int o=32;o>0;o>>=1) v = fmaxf(v,__shfl_xor(v,o,64)); return v; }

// ---------------- K0: tiled transposes + W1 split/swizzle ----------------
__global__ __launch_bounds__(256) void k0_transpose(const float* ipw, const float* ow, const float* mw1,
                             float* WT, float* OWT, _Float16* w1hi, _Float16* w1lo){
  int bid = blockIdx.x;
  if(bid < 768){
    __shared__ float t[32][33];
    int tdin = bid & 15, tdout = bid >> 4;
    int tx = threadIdx.x & 31, ty = threadIdx.x >> 5;
    int dout0 = tdout*32, din0 = tdin*32;
    for(int r=ty; r<32; r+=8) t[r][tx] = ipw[(size_t)(dout0+r)*512 + din0+tx];
    __syncthreads();
    for(int r=ty; r<32; r+=8) WT[(size_t)(din0+r)*1536 + dout0+tx] = t[tx][r];
  } else if(bid < 1024){
    __shared__ float t[32][33];
    int b2 = bid - 768;
    int tdin = b2 & 15, tdout = b2 >> 4;
    int tx = threadIdx.x & 31, ty = threadIdx.x >> 5;
    int dout0 = tdout*32, din0 = tdin*32;
    for(int r=ty; r<32; r+=8) t[r][tx] = ow[(size_t)(dout0+r)*512 + din0+tx];
    __syncthreads();
    for(int r=ty; r<32; r+=8) OWT[(size_t)(din0+r)*512 + dout0+tx] = t[tx][r];
  } else {
    int i3 = (bid-1024)*256 + threadIdx.x;
    int t = i3&7, ln = (i3>>3)&63, J = (i3>>9)&31, T = i3>>14;
    int j = J*16 + (ln&15);
    int d = T*32 + ((ln>>4)<<3) + t;
    float w = mw1[j*512 + d] * 64.0f;
    _Float16 hi = (_Float16)w;
    _Float16 lo = (_Float16)(w - (float)hi);
    w1hi[i3] = hi; w1lo[i3] = lo;
  }
}

// ---------------- K1: q = LN(text) @ Wq^T + bq  (154 blocks: k x half) ----------------
__global__ __launch_bounds__(256) void k1_q(const float* text, const float* ipb,
                                            const float* g1, const float* b1p,
                                            const float* WT, float* qws){
  int k = blockIdx.x >> 1, half = blockIdx.x & 1;
  int tid = threadIdx.x;
  __shared__ float xln[512];
  __shared__ float rA[4], rB[4];
  float x0 = text[k*512+tid], x1 = text[k*512+256+tid];
  float s1 = wsumf(x0+x1), s2 = wsumf(x0*x0+x1*x1);
  int w = tid>>6, ln = tid&63;
  if(!ln){ rA[w]=s1; rB[w]=s2; }
  __syncthreads();
  float mu = (rA[0]+rA[1]+rA[2]+rA[3])*(1.f/512.f);
  float var = (rB[0]+rB[1]+rB[2]+rB[3])*(1.f/512.f) - mu*mu;
  float rs = 1.f/sqrtf(fmaxf(var,0.f) + 1e-5f);
  xln[tid]     = (x0-mu)*rs*g1[tid]     + b1p[tid];
  xln[tid+256] = (x1-mu)*rs*g1[tid+256] + b1p[tid+256];
  __syncthreads();
  int d = half*256 + tid;
  float a0=0.f,a1=0.f,a2=0.f,a3=0.f;   // 4 independent chains for ILP
  for(int din=0; din<512; din+=4){
    a0 += xln[din  ] * WT[(din  )*1536 + d];
    a1 += xln[din+1] * WT[(din+1)*1536 + d];
    a2 += xln[din+2] * WT[(din+2)*1536 + d];
    a3 += xln[din+3] * WT[(din+3)*1536 + d];
  }
  qws[k*512+d] = ipb[d] + ((a0+a1)+(a2+a3));
}

// ---------------- K2: k = LN(F)@Wk^T+bk, v = F@Wv^T+bv  (4 rows/block, 392 blocks) ----
__global__ __launch_bounds__(512) void k2_kv(const float* F, const float* ipb,
                                             const float* g1, const float* b1p,
                                             const float* WT, float* kmat, float* vmat){
  int r0 = blockIdx.x*4; int tid = threadIdx.x;
  __shared__ float xs[4][512];
  __shared__ float xl[4][512];
  __shared__ float red[4][64];
  __shared__ float mu4[4], rs4[4];
  for(int e=tid; e<2048; e+=512){ int r=e>>9, d=e&511; xs[r][d] = F[(size_t)(r0+r)*512 + d]; }
  __syncthreads();
  {
    float s=0.f, q=0.f; int r=0, t=0;
    if(tid<256){
      r = tid>>6; t = tid&63;
      for(int i=0;i<8;++i){ float v = xs[r][t+64*i]; s+=v; q+=v*v; }
      red[r][t] = s;
    }
    __syncthreads();
    if(tid<4){ float ss=0; for(int i=0;i<64;++i) ss+=red[tid][i]; mu4[tid]=ss*(1.f/512.f); }
    __syncthreads();
    if(tid<256) red[r][t] = q;
    __syncthreads();
    if(tid<4){ float qq=0; for(int i=0;i<64;++i) qq+=red[tid][i];
      float m=mu4[tid]; rs4[tid]=1.f/sqrtf(fmaxf(qq*(1.f/512.f)-m*m,0.f)+1e-5f); }
    __syncthreads();
  }
  for(int e=tid; e<2048; e+=512){ int r=e>>9, d=e&511;
    xl[r][d] = (xs[r][d]-mu4[r])*rs4[r]*g1[d] + b1p[d]; }
  __syncthreads();
  int d=tid;
  float ak[4], av[4];
  float bk=ipb[512+d], bv=ipb[1024+d];
  #pragma unroll
  for(int r=0;r<4;++r){ ak[r]=bk; av[r]=bv; }
  for(int din=0; din<512; din+=4){
    float wk[4], wv[4];
    #pragma unroll
    for(int u=0;u<4;++u){ wk[u]=WT[(din+u)*1536+512+d]; wv[u]=WT[(din+u)*1536+1024+d]; }
    #pragma unroll
    for(int r=0;r<4;++r){
      float4 a4 = *(const float4*)&xl[r][din];
      float4 x4 = *(const float4*)&xs[r][din];
      ak[r] += a4.x*wk[0]+a4.y*wk[1]+a4.z*wk[2]+a4.w*wk[3];
      av[r] += x4.x*wv[0]+x4.y*wv[1]+x4.z*wv[2]+x4.w*wv[3];
    }
  }
  #pragma unroll
  for(int r=0;r<4;++r){
    size_t base = (size_t)(r0+r)*512;
    kmat[base+d]=ak[r]; vmat[base+d]=av[r];
  }
}

// ---------------- K3: scores + softmax (640 blocks: kc x b x h) ----------------
__global__ __launch_bounds__(256) void k3_attn(const float* qws, const float* kmat, float* attf){
  int bid = blockIdx.x;
  int kc = bid>>6, b = (bid>>3)&7, h = bid&7;
  int tid = threadIdx.x; int n = tid; int w = tid>>6, ln = tid&63;
  __shared__ float qb[8][64];
  __shared__ float rM[8][4], rS[8][4];
  float4 kr[16];
  if(n < 196){
    const float4* kp = (const float4*)(kmat + ((size_t)(b*196+n))*512 + h*64);
    #pragma unroll
    for(int j=0;j<16;++j) kr[j] = kp[j];
  }
  int kbase = kc*8;
  for(int e=tid; e<512; e+=256){ int kk=e>>6, j=e&63; int k=kbase+kk;
    qb[kk][j] = (k<77)? qws[k*512 + h*64 + j] : 0.f; }
  __syncthreads();
  float sc[8];
  #pragma unroll
  for(int kk=0;kk<8;++kk){
    float s = 0.f;
    if(n<196){
      const float4* q4 = (const float4*)qb[kk];
      #pragma unroll
      for(int j=0;j<16;++j){ float4 q = q4[j];
        s += q.x*kr[j].x + q.y*kr[j].y + q.z*kr[j].z + q.w*kr[j].w; }
      sc[kk] = s*0.125f;
    } else sc[kk] = -INFINITY;
  }
  #pragma unroll
  for(int kk=0;kk<8;++kk){ float m = wmaxf(sc[kk]); if(!ln) rM[kk][w]=m; }
  __syncthreads();
  float ex[8];
  #pragma unroll
  for(int kk=0;kk<8;++kk){
    float m = fmaxf(fmaxf(rM[kk][0],rM[kk][1]),fmaxf(rM[kk][2],rM[kk][3]));
    float e = expf(sc[kk]-m);
    ex[kk]=e;
    float s = wsumf(e); if(!ln) rS[kk][w]=s;
  }
  __syncthreads();
  #pragma unroll
  for(int kk=0;kk<8;++kk){
    int k = kbase+kk;
    if(k<77 && n<196){
      float tot = rS[kk][0]+rS[kk][1]+rS[kk][2]+rS[kk][3];
      attf[(((size_t)(b*8+h))*77 + k)*196 + n] = ex[kk]/tot;
    }
  }
}

// ---------------- K4: ctx = attn @ v (640 blocks: kc x b x h) ----------------
__global__ __launch_bounds__(256) void k4_ctx(const float* attf, const float* vmat, float* ctx){
  int bid = blockIdx.x;
  int kc = bid>>6, b = (bid>>3)&7, h = bid&7;
  int tid = threadIdx.x; int ng = tid>>6, j = tid&63;
  __shared__ float vT[196][64];
  __shared__ float aT[8][196];
  __shared__ float red[8][4][64];
  for(int e=tid; e<196*16; e+=256){ int n=e>>4, jc=e&15;
    const float4* vp = (const float4*)(vmat + ((size_t)(b*196+n))*512 + h*64);
    *(float4*)&vT[n][jc*4] = vp[jc];
  }
  int kbase=kc*8;
  for(int e=tid; e<8*196; e+=256){ int kk=e/196, n=e-kk*196; int k=kbase+kk;
    aT[kk][n] = (k<77)? attf[(((size_t)(b*8+h))*77+k)*196+n] : 0.f; }
  __syncthreads();
  float vr[49];
  #pragma unroll
  for(int t=0;t<49;++t) vr[t] = vT[ng*49+t][j];
  #pragma unroll
  for(int kk=0;kk<8;++kk){
    float p=0.f;
    #pragma unroll
    for(int t=0;t<49;++t) p += aT[kk][ng*49+t]*vr[t];
    red[kk][ng][j]=p;
  }
  __syncthreads();
  for(int e=tid; e<512; e+=256){ int kk=e>>6, j2=e&63; int k=kbase+kk;
    if(k<77){
      float s = red[kk][0][j2]+red[kk][1][j2]+red[kk][2][j2]+red[kk][3][j2];
      ctx[((size_t)(b*77+k))*512 + h*64 + j2] = s;
    } }
}

// ---------------- K5: attn_weights = mean over H ----------------
__global__ void k5_attw(const float* attf, float* attw, float* out2){
  int idx = blockIdx.x*256+threadIdx.x;
  if(idx >= 8*77*196) return;
  int b = idx / (77*196); int rem = idx - b*(77*196);
  float s=0.f;
  #pragma unroll
  for(int h=0;h<8;++h) s += attf[((size_t)(b*8+h))*77*196 + rem];
  s *= 0.125f;
  attw[idx]=s; out2[idx]=s;
}

// ---------------- K6: AO = LN2(ctx @ out_w^T + out_b)  (4 rows/block, 154 blocks) ----
__global__ __launch_bounds__(512) void k6_ao(const float* ctx, const float* OWT,
                                             const float* ob, const float* g2, const float* b2p,
                                             float* AO){
  int R0 = blockIdx.x*4; int tid = threadIdx.x;
  __shared__ float xs[4][512];
  __shared__ float ao[4][512];
  __shared__ float red[4][64];
  __shared__ float mu4[4], rs4[4];
  for(int e=tid;e<2048;e+=512){ int r=e>>9,d=e&511; xs[r][d]=ctx[(size_t)(R0+r)*512+d]; }
  __syncthreads();
  int d=tid;
  float a[4]; float obv=ob[d];
  #pragma unroll
  for(int r=0;r<4;++r) a[r]=obv;
  for(int din=0;din<512;din+=4){
    float wv[4];
    #pragma unroll
    for(int u=0;u<4;++u) wv[u]=OWT[(din+u)*512+d];
    #pragma unroll
    for(int r=0;r<4;++r){
      float4 x4 = *(const float4*)&xs[r][din];
      a[r] += x4.x*wv[0]+x4.y*wv[1]+x4.z*wv[2]+x4.w*wv[3];
    }
  }
  #pragma unroll
  for(int r=0;r<4;++r) ao[r][d]=a[r];
  __syncthreads();
  {
    float s=0.f,q=0.f; int r=0,t=0;
    if(tid<256){
      r=tid>>6; t=tid&63;
      for(int i=0;i<8;++i){ float v=ao[r][t+64*i]; s+=v; q+=v*v; }
      red[r][t]=s;
    }
    __syncthreads();
    if(tid<4){ float ss=0; for(int i=0;i<64;++i) ss+=red[tid][i]; mu4[tid]=ss*(1.f/512.f); }
    __syncthreads();
    if(tid<256) red[r][t]=q;
    __syncthreads();
    if(tid<4){ float qq=0; for(int i=0;i<64;++i) qq+=red[tid][i];
      float m=mu4[tid]; rs4[tid]=1.f/sqrtf(fmaxf(qq*(1.f/512.f)-m*m,0.f)+1e-5f); }
    __syncthreads();
  }
  for(int e=tid;e<2048;e+=512){ int r=e>>9,dd=e&511;
    AO[(size_t)(R0+r)*512+dd] = (ao[r][dd]-mu4[r])*rs4[r]*g2[dd] + b2p[dd]; }
}

// ---------------- K6b: Sv = (1/77) attw^T @ AO per (b, 8-n tile); wsum ---------
__global__ __launch_bounds__(512) void k6b_sv(const float* AO, const float* attw,
                                              float* Svws, float* wsumws){
  int bid = blockIdx.x;
  int b = bid/25, nt = bid - b*25;
  int n0 = nt*8;
  int tid = threadIdx.x;
  __shared__ float wsK[80][8];
  for(int e=tid; e<640; e+=512){ int k=e>>3, r=e&7; int n=n0+r;
    wsK[k][r] = (k<77 && n<196)? attw[((size_t)(b*77+k))*196 + n] : 0.f; }
  __syncthreads();
  if(tid<8){ int n=n0+tid;
    if(n<196){ float s=0.f;
      for(int k=0;k<77;++k) s+=wsK[k][tid];
      wsumws[b*196+n]=s; } }
  int d = tid;
  float acc[8];
  #pragma unroll
  for(int r=0;r<8;++r) acc[r]=0.f;
  const float* aob = AO + (size_t)b*77*512 + d;
  for(int k=0;k<77;++k){
    float a = aob[(size_t)k*512];
    #pragma unroll
    for(int r=0;r<8;++r) acc[r] += wsK[k][r]*a;
  }
  #pragma unroll
  for(int r=0;r<8;++r){ int n=n0+r; if(n<196)
    Svws[((size_t)(b*196+n))*512 + d] = acc[r]*(1.f/77.f); }
}

// ---------------- K7: per-(b,n,chunk) fused MLP; A LDS-resident, barrier-free t-loop
// 5 uniform chunks of MT=1 (16 rows each; chunk 4 masks rows 77..79).
// A-LDS 32KB, struct ~43KB -> 3 blocks/CU -> 24 waves/CU -> VGPR cap ~85;
// live ~64 arch + 16 AGPR = 80, no spill. t-loop: 2-Bset ping-pong
// (R12/R14-proven), ds_read A, MFMA, zero barriers. Budget rule (R13 lesson):
// arch + AGPR must fit cap; depth-2 prefetch does NOT fit - don't reintroduce.
struct __align__(16) K7Smem {
  _Float16 Ah[16*512];      // [t][pos 0..63][8], pos=(lane+t)&63
  _Float16 Al[16*512];
  float b1s[512], gs[512], bs[512];
  float wvS[80];
  float redS[8][16], redQ[8][16];
  float muA[16], rsA[16];
  float gfin[512];
  float qred[320];
};   // ~43 KB -> 3 blocks/CU

#define K7_MFMA3(ACC, AFH, AFL, BH, BL) \
  ACC = __builtin_amdgcn_mfma_f32_16x16x32_f16(AFL, BH, ACC, 0,0,0); \
  ACC = __builtin_amdgcn_mfma_f32_16x16x32_f16(AFH, BL, ACC, 0,0,0); \
  ACC = __builtin_amdgcn_mfma_f32_16x16x32_f16(AFH, BH, ACC, 0,0,0);

struct Bset { f16x8 h0,h1,h2,h3,l0,l1,l2,l3; };

DI void loadB(Bset& s, const _Float16* bph, const _Float16* bpl, int t){
  const _Float16* ph = bph + t*16384;
  const _Float16* pl = bpl + t*16384;
  s.h0 = *(const f16x8*)(ph);       s.h1 = *(const f16x8*)(ph+512);
  s.h2 = *(const f16x8*)(ph+1024);  s.h3 = *(const f16x8*)(ph+1536);
  s.l0 = *(const f16x8*)(pl);       s.l1 = *(const f16x8*)(pl+512);
  s.l2 = *(const f16x8*)(pl+1024);  s.l3 = *(const f16x8*)(pl+1536);
}

DI void stepMFMA1(f32x4 acc[4], const _Float16* Ah, const _Float16* Al,
                  const Bset& B, int t, int ln){
  int off = t*512 + ((ln + t)&63)*8;
  f16x8 fh = *(const f16x8*)&Ah[off];
  f16x8 fl = *(const f16x8*)&Al[off];
  K7_MFMA3(acc[0], fh, fl, B.h0, B.l0)
  K7_MFMA3(acc[1], fh, fl, B.h1, B.l1)
  K7_MFMA3(acc[2], fh, fl, B.h2, B.l2)
  K7_MFMA3(acc[3], fh, fl, B.h3, B.l3)
}

template<int K0>
DI void k7_body(int bn, const float* F, const float* AO, const float* attw,
                const _Float16* w1hi, const _Float16* w1lo,
                const float* b1p, const float* lng, const float* lnb,
                const float* w2, const float* b2p,
                const float* Svws, const float* wsumws,
                float* Qpws, K7Smem& sm){
  int b = bn/196, n = bn - b*196;
  int tid = threadIdx.x; int w = tid>>6, ln = tid&63;
  int col = ln&15, quad = ln>>4;
  const float* AObase = AO + (size_t)b*77*512;
  sm.b1s[tid] = b1p[tid]; sm.gs[tid] = lng[tid]; sm.bs[tid] = lnb[tid];
  if(tid<80) sm.wvS[tid] = (tid<77)? attw[((size_t)(b*77+tid))*196+n] : 0.f;
  __syncthreads();

  // ---- stage clean (hi/lo) for the 16 rows into LDS; this thread owns fixed d0
  {
    int d0 = (tid&63)*8;            // fixed k-slice for this thread
    int r0 = tid>>6;                // base row 0..7 (+8 on 2nd step)
    int t  = d0>>5;
    int k8 = (d0&31)>>3;
    float4 f0 = *(const float4*)&F[(size_t)bn*512 + d0];
    float4 f1 = *(const float4*)&F[(size_t)bn*512 + d0+4];
    float4 sv0 = *(const float4*)&Svws[(size_t)bn*512 + d0];
    float4 sv1 = *(const float4*)&Svws[(size_t)bn*512 + d0+4];
    float fk[8] = {f0.x*1024.f,f0.y*1024.f,f0.z*1024.f,f0.w*1024.f,
                   f1.x*1024.f,f1.y*1024.f,f1.z*1024.f,f1.w*1024.f};
    float sv[8] = {sv0.x,sv0.y,sv0.z,sv0.w,sv1.x,sv1.y,sv1.z,sv1.w};
    #pragma unroll
    for(int it=0; it<2; ++it){
      int row = r0 + it*8;          // local row 0..15
      int grow = K0 + row;
      bool ok = grow < 77;
      int rl = ok ? grow : 0;
      float wm = ok ? sm.wvS[grow] : 0.f;
      const float* ap = AObase + (size_t)rl*512 + d0;
      float4 a0 = *(const float4*)ap;
      float4 a1 = *(const float4*)(ap+4);
      float av[8] = {a0.x,a0.y,a0.z,a0.w,a1.x,a1.y,a1.z,a1.w};
      f16x8 hfrag, lfrag;
      #pragma unroll
      for(int i=0;i<8;++i){
        float c = ok ? fk[i]*(wm*av[i] - sv[i]) : 0.f;
        _Float16 h = (_Float16)c;
        hfrag[i] = h;
        lfrag[i] = (_Float16)(c - (float)h);
      }
      int lane = row | (k8<<4);     // row<16
      int pos = (lane + t)&63;
      int idx = t*512 + pos*8;
      *(f16x8*)&sm.Ah[idx] = hfrag;
      *(f16x8*)&sm.Al[idx] = lfrag;
    }
  }
  __syncthreads();
  // ---- barrier-free t-loop: A from LDS, B 2-set ping-pong from global ----
  f32x4 acc[4];
  #pragma unroll
  for(int jj=0;jj<4;++jj) acc[jj] = (f32x4){0.f,0.f,0.f,0.f};

  const _Float16* bph = w1hi + ((w*4)*64 + ln)*8;  // +512 per jj, +16384 per t
  const _Float16* bpl = w1lo + ((w*4)*64 + ln)*8;

  Bset s0, s1;
  loadB(s0, bph, bpl, 0);
  #pragma unroll 1
  for(int tt=0; tt<16; tt+=2){
    loadB(s1, bph, bpl, tt+1);                 // prefetch odd step
    stepMFMA1(acc, sm.Ah, sm.Al, s0, tt, ln);
    if(tt+2<16) loadB(s0, bph, bpl, tt+2);     // prefetch next even step
    stepMFMA1(acc, sm.Ah, sm.Al, s1, tt+1, ln);
  }

  const float UNS = 1.f/65536.f;
  {
    float s[4]={0.f,0.f,0.f,0.f}, q[4]={0.f,0.f,0.f,0.f};
    #pragma unroll
    for(int jj=0;jj<4;++jj){
      int j = w*64 + jj*16 + col; float bj = sm.b1s[j];
      #pragma unroll
      for(int r=0;r<4;++r){
        float h = acc[jj][r]*UNS + bj;
        s[r]+=h; q[r]+=h*h;
      }
    }
    #pragma unroll
    for(int r=0;r<4;++r){
      #pragma unroll
      for(int o=1;o<16;o<<=1){ s[r]+=__shfl_xor(s[r],o,64); q[r]+=__shfl_xor(q[r],o,64); }
    }
    if(col==0){
      #pragma unroll
      for(int r=0;r<4;++r){ int row = quad*4+r; sm.redS[w][row]=s[r]; sm.redQ[w][row]=q[r]; }
    }
  }
  __syncthreads();
  if(tid<16){
    float s=0.f,q=0.f;
    #pragma unroll
    for(int ww=0;ww<8;++ww){ s+=sm.redS[ww][tid]; q+=sm.redQ[ww][tid]; }
    float mu = s*(1.f/512.f);
    float var = q*(1.f/512.f)-mu*mu;
    sm.muA[tid]=mu; sm.rsA[tid]=1.f/sqrtf(fmaxf(var,0.f)+1e-5f);
  }
  __syncthreads();
  float gp[4]={0.f,0.f,0.f,0.f};
  #pragma unroll
  for(int r=0;r<4;++r){
    int lr = quad*4+r;
    float mu=sm.muA[lr], rs=sm.rsA[lr], wk=sm.wvS[K0+lr];
    #pragma unroll
    for(int jj=0;jj<4;++jj){
      int j = w*64 + jj*16 + col;
      float h = acc[jj][r]*UNS + sm.b1s[j];
      float x = (h-mu)*rs;
      float y = x*sm.gs[j]+sm.bs[j];
      float gl = 0.5f*y*(1.f+erff(y*0.70710678118654752f));
      gp[jj] += wk*gl;
    }
  }
  #pragma unroll
  for(int jj=0;jj<4;++jj){ gp[jj]+=__shfl_xor(gp[jj],16,64); gp[jj]+=__shfl_xor(gp[jj],32,64); }
  if(ln<16){
    #pragma unroll
    for(int jj=0;jj<4;++jj) sm.gfin[w*64 + jj*16 + ln] = gp[jj];
  }
  __syncthreads();
  if(tid<320){ int m=tid>>4, seg=tid&15; float p=0.f;
    for(int u=0;u<32;++u){ int uu=(u+seg)&31; int j=seg*32+uu;   // rotated: per-lane distinct banks
      p += sm.gfin[j]*w2[m*512+j]; }
    sm.qred[m*16+seg]=p; }
  __syncthreads();
  if(tid<20){ float s=0.f;
    for(int seg=0;seg<16;++seg) s+=sm.qred[tid*16+seg];
    if(K0==0) s += b2p[tid]*wsumws[bn];          // bias term once, in chunk 0
    Qpws[(size_t)bn*100 + (K0>>4)*20 + tid]=s; }
}

__global__
__attribute__((amdgpu_flat_work_group_size(512,512)))
void k7_mlp(const float* F, const float* AO, const float* attw,
            const _Float16* w1hi, const _Float16* w1lo,
            const float* b1p, const float* lng, const float* lnb,
            const float* w2, const float* b2p,
            const float* Svws, const float* wsumws,
            float* Qpws){
  __shared__ K7Smem sm;
  int bid = blockIdx.x;
  int bn = bid/5;
  int c = bid - bn*5;
  switch(c){
    case 0: k7_body<0 >(bn,F,AO,attw,w1hi,w1lo,b1p,lng,lnb,w2,b2p,Svws,wsumws,Qpws,sm); break;
    case 1: k7_body<16>(bn,F,AO,attw,w1hi,w1lo,b1p,lng,lnb,w2,b2p,Svws,wsumws,Qpws,sm); break;
    case 2: k7_body<32>(bn,F,AO,attw,w1hi,w1lo,b1p,lng,lnb,w2,b2p,Svws,wsumws,Qpws,sm); break;
    case 3: k7_body<48>(bn,F,AO,attw,w1hi,w1lo,b1p,lng,lnb,w2,b2p,Svws,wsumws,Qpws,sm); break;
    default:k7_body<64>(bn,F,AO,attw,w1hi,w1lo,b1p,lng,lnb,w2,b2p,Svws,wsumws,Qpws,sm); break;
  }
}

// ---------------- K8: per-(b,n) top-51 mask + normalize -> out1 ----------------
__global__ __launch_bounds__(256) void k8_topk(const float* F, const float* T,
                                               const float* Qpws, float* out1){
  int bn = blockIdx.x; int tid = threadIdx.x;
  int w = tid>>6, ln = tid&63;
  __shared__ float Fv[512];
  __shared__ float QpS[20];
  __shared__ float ninv[20];
  __shared__ unsigned char selb[20][64];
  for(int e=tid;e<512;e+=256) Fv[e]=F[(size_t)bn*512+e];
  if(tid<20){
    const float* qp = Qpws + (size_t)bn*100 + tid;
    QpS[tid] = qp[0]+qp[20]+qp[40]+qp[60]+qp[80];
  }
  __syncthreads();
  for(int rr=0; rr<5; ++rr){
    int m = rr*4 + w;
    float qv[8]; uint key[8];
    const float4* tp = (const float4*)(T + (size_t)m*512 + ln*8);
    float4 t0 = tp[0], t1 = tp[1];
    float tf[8] = {t0.x,t0.y,t0.z,t0.w,t1.x,t1.y,t1.z,t1.w};
    float qp = QpS[m];
    #pragma unroll
    for(int i=0;i<8;++i){ float p = Fv[ln*8+i]*tf[i]; qv[i]=p*qp;
      key[i]=__float_as_uint(qv[i])&0x7fffffffu; }
    uint th=0u;
    for(int bit=30; bit>=0; --bit){
      uint cand = th | (1u<<bit);
      int c=0;
      #pragma unroll
      for(int i=0;i<8;++i) c += (int)__popcll(__ballot(key[i]>=cand));
      if(c>=51) th=cand;
    }
    int cg=0;
    #pragma unroll
    for(int i=0;i<8;++i) cg += (int)__popcll(__ballot(key[i]>th));
    int rneed = 51-cg;
    int eqc=0;
    #pragma unroll
    for(int i=0;i<8;++i) eqc += (key[i]==th);
    int pre=eqc;
    for(int o=1;o<64;o<<=1){ int v=__shfl_up(pre,o,64); if(ln>=o) pre+=v; }
    pre -= eqc;
    unsigned char mbits=0; float ss=0.f; int rk=pre;
    #pragma unroll
    for(int i=0;i<8;++i){
      bool s;
      if(key[i]>th) s=true;
      else if(key[i]==th){ s = (rk<rneed); rk++; }
      else s=false;
      if(s){ mbits |= (unsigned char)(1u<<i); ss += qv[i]*qv[i]; }
    }
    ss = wsumf(ss);
    if(ln==0) ninv[m] = 1.f/fmaxf(sqrtf(ss),1e-6f);
    selb[m][ln]=mbits;
  }
  __syncthreads();
  size_t base=(size_t)bn*10240;
  for(int e=tid;e<10240;e+=256){
    int d=e/20, mm=e-d*20;
    float val=0.f;
    if((selb[mm][d>>3]>>(d&7))&1){
      val = Fv[d]*T[(size_t)mm*512+d]*QpS[mm]*ninv[mm];
    }
    out1[base+e]=val;
  }
}

extern "C" void kernel_launch(void* const* d_in, const int* in_sizes, int n_in,
                              void* d_out, int out_size, void* d_ws, size_t ws_size,
                              hipStream_t stream){
  const float* F    = (const float*)d_in[0];
  const float* text = (const float*)d_in[1];
  const float* ipw  = (const float*)d_in[2];
  const float* ipb  = (const float*)d_in[3];
  const float* outw = (const float*)d_in[4];
  const float* outb = (const float*)d_in[5];
  const float* g1   = (const float*)d_in[6];
  const float* b1   = (const float*)d_in[7];
  const float* g2   = (const float*)d_in[8];
  const float* b2   = (const float*)d_in[9];
  const float* mw1  = (const float*)d_in[10];
  const float* mb1  = (const float*)d_in[11];
  const float* mlg  = (const float*)d_in[12];
  const float* mlb  = (const float*)d_in[13];
  const float* mw2  = (const float*)d_in[14];
  const float* mb2  = (const float*)d_in[15];
  const float* tmpl = (const float*)d_in[16];
  float* ws = (float*)d_ws;
  float* WT   = ws;
  float* OWT  = ws +  786432;
  float* qws  = ws + 1048576;
  float* kmat = ws + 1088000;
  float* vmat = ws + 1890816;
  float* attf = ws + 2693632;
  float* attw = ws + 3659520;
  float* ctx  = ws + 3780256;
  float* AO   = ws + 4095648;
  _Float16* w1hi = (_Float16*)(ws + 4473760);
  _Float16* w1lo = (_Float16*)(ws + 4604832);
  // dead-region reuse:
  float* wsum = ws + 1048576;   // old qws region (dead after k3)
  float* Sv   = ws + 1088000;   // old kmat region (dead after k3, exact fit)
  float* Qp   = ws +  786432;   // old OWT region (dead after k6; 156800 fl <= 262144)
  float* out1 = (float*)d_out;
  float* out2 = out1 + 16056320;

  hipLaunchKernelGGL(k0_transpose, dim3(2048), dim3(256), 0, stream, ipw, outw, mw1, WT, OWT, w1hi, w1lo);
  hipLaunchKernelGGL(k1_q,   dim3(154), dim3(256), 0, stream, text, ipb, g1, b1, WT, qws);
  hipLaunchKernelGGL(k2_kv,  dim3(392), dim3(512), 0, stream, F, ipb, g1, b1, WT, kmat, vmat);
  hipLaunchKernelGGL(k3_attn,dim3(640), dim3(256), 0, stream, qws, kmat, attf);
  hipLaunchKernelGGL(k4_ctx, dim3(640), dim3(256), 0, stream, attf, vmat, ctx);
  hipLaunchKernelGGL(k5_attw,dim3(472), dim3(256), 0, stream, attf, attw, out2);
  hipLaunchKernelGGL(k6_ao,  dim3(154), dim3(512), 0, stream, ctx, OWT, outb, g2, b2, AO);
  hipLaunchKernelGGL(k6b_sv, dim3(200), dim3(512), 0, stream, AO, attw, Sv, wsum);
  hipLaunchKernelGGL(k7_mlp, dim3(7840),dim3(512), 0, stream, F, AO, attw, w1hi, w1lo, mb1, mlg, mlb, mw2, mb2, Sv, wsum, Qp);
  hipLaunchKernelGGL(k8_topk,dim3(1568),dim3(256), 0, stream, F, tmpl, Qp, out1);
}

// Round 10
// 607.577 us; speedup vs baseline: 1.1686x; 1.1686x over previous
//
#include <hip/hip_runtime.h>
#include <hip/hip_bf16.h>
#include <math.h>

// B=8 N=196 D=512 M=20 K=77 H=8 hd=64, keep=51.  All inputs/outputs fp32.
// out1 = Qs/nrm (B,N,D,M) 16,056,320 fl; out2 = attn_weights (B,K,N) 120,736 fl
// Workspace layout: see kernel_launch. Dead-region reuse:
//   wsum -> qws (@1048576, dead after k3), Sv -> kmat (@1088000, dead after k3),
//   Qp -> OWT (@786432, dead after k6).
//
// R16 (post-mortem R15: 5-chunk split regressed 303->435us; k7 time tracks
// B-traffic/18TB/s exactly (R12 4.7GB->267us, R15 7.84GB->435us) => k7 is
// L2->CU B-stream bound; 32 rows/block @ 2blk/CU is the LDS-max = 261us floor):
//  1. k7 reverted to proven 3-chunk MT=2,2,1 (R12/R14: 267-303us, VGPR 64).
//  2. A-LDS permutation pos=(P+t)&63 with P=((ln&15)<<2)|(ln>>4): bank residue
//     (4r+k8+t)%8 uniform on BOTH ds_write (k8,t vary) and ds_read (r,k8 vary)
//     -> kills the remaining 6.1M conflict cycles. P is per-thread constant.
//  3. k6 4-row split kept from R15 (all-CU coverage, uninvolved in regression).

typedef unsigned int uint;
typedef _Float16 f16x8 __attribute__((ext_vector_type(8)));
typedef float f32x4 __attribute__((ext_vector_type(4)));

#define DI __device__ __forceinline__

DI float wsumf(float v){ for(int o=32;o>0;o>>=1) v += __shfl_xor(v,o,64); return v; }
DI int   wsumi(int v){ for(int o=32;o>0;o>>=1) v += __shfl_xor(v,o,64); return v; }
DI float wmaxf(float v){ for(int o=32;o>0;o>>=1) v = fmaxf(v,__shfl_xor(v,o,64)); return v; }

// ---------------- K0: tiled transposes + W1 split/swizzle ----------------
__global__ __launch_bounds__(256) void k0_transpose(const float* ipw, const float* ow, const float* mw1,
                             float* WT, float* OWT, _Float16* w1hi, _Float16* w1lo){
  int bid = blockIdx.x;
  if(bid < 768){
    __shared__ float t[32][33];
    int tdin = bid & 15, tdout = bid >> 4;
    int tx = threadIdx.x & 31, ty = threadIdx.x >> 5;
    int dout0 = tdout*32, din0 = tdin*32;
    for(int r=ty; r<32; r+=8) t[r][tx] = ipw[(size_t)(dout0+r)*512 + din0+tx];
    __syncthreads();
    for(int r=ty; r<32; r+=8) WT[(size_t)(din0+r)*1536 + dout0+tx] = t[tx][r];
  } else if(bid < 1024){
    __shared__ float t[32][33];
    int b2 = bid - 768;
    int tdin = b2 & 15, tdout = b2 >> 4;
    int tx = threadIdx.x & 31, ty = threadIdx.x >> 5;
    int dout0 = tdout*32, din0 = tdin*32;
    for(int r=ty; r<32; r+=8) t[r][tx] = ow[(size_t)(dout0+r)*512 + din0+tx];
    __syncthreads();
    for(int r=ty; r<32; r+=8) OWT[(size_t)(din0+r)*512 + dout0+tx] = t[tx][r];
  } else {
    int i3 = (bid-1024)*256 + threadIdx.x;
    int t = i3&7, ln = (i3>>3)&63, J = (i3>>9)&31, T = i3>>14;
    int j = J*16 + (ln&15);
    int d = T*32 + ((ln>>4)<<3) + t;
    float w = mw1[j*512 + d] * 64.0f;
    _Float16 hi = (_Float16)w;
    _Float16 lo = (_Float16)(w - (float)hi);
    w1hi[i3] = hi; w1lo[i3] = lo;
  }
}

// ---------------- K1: q = LN(text) @ Wq^T + bq  (154 blocks: k x half) ----------------
__global__ __launch_bounds__(256) void k1_q(const float* text, const float* ipb,
                                            const float* g1, const float* b1p,
                                            const float* WT, float* qws){
  int k = blockIdx.x >> 1, half = blockIdx.x & 1;
  int tid = threadIdx.x;
  __shared__ float xln[512];
  __shared__ float rA[4], rB[4];
  float x0 = text[k*512+tid], x1 = text[k*512+256+tid];
  float s1 = wsumf(x0+x1), s2 = wsumf(x0*x0+x1*x1);
  int w = tid>>6, ln = tid&63;
  if(!ln){ rA[w]=s1; rB[w]=s2; }
  __syncthreads();
  float mu = (rA[0]+rA[1]+rA[2]+rA[3])*(1.f/512.f);
  float var = (rB[0]+rB[1]+rB[2]+rB[3])*(1.f/512.f) - mu*mu;
  float rs = 1.f/sqrtf(fmaxf(var,0.f) + 1e-5f);
  xln[tid]     = (x0-mu)*rs*g1[tid]     + b1p[tid];
  xln[tid+256] = (x1-mu)*rs*g1[tid+256] + b1p[tid+256];
  __syncthreads();
  int d = half*256 + tid;
  float a0=0.f,a1=0.f,a2=0.f,a3=0.f;   // 4 independent chains for ILP
  for(int din=0; din<512; din+=4){
    a0 += xln[din  ] * WT[(din  )*1536 + d];
    a1 += xln[din+1] * WT[(din+1)*1536 + d];
    a2 += xln[din+2] * WT[(din+2)*1536 + d];
    a3 += xln[din+3] * WT[(din+3)*1536 + d];
  }
  qws[k*512+d] = ipb[d] + ((a0+a1)+(a2+a3));
}

// ---------------- K2: k = LN(F)@Wk^T+bk, v = F@Wv^T+bv  (4 rows/block, 392 blocks) ----
__global__ __launch_bounds__(512) void k2_kv(const float* F, const float* ipb,
                                             const float* g1, const float* b1p,
                                             const float* WT, float* kmat, float* vmat){
  int r0 = blockIdx.x*4; int tid = threadIdx.x;
  __shared__ float xs[4][512];
  __shared__ float xl[4][512];
  __shared__ float red[4][64];
  __shared__ float mu4[4], rs4[4];
  for(int e=tid; e<2048; e+=512){ int r=e>>9, d=e&511; xs[r][d] = F[(size_t)(r0+r)*512 + d]; }
  __syncthreads();
  {
    float s=0.f, q=0.f; int r=0, t=0;
    if(tid<256){
      r = tid>>6; t = tid&63;
      for(int i=0;i<8;++i){ float v = xs[r][t+64*i]; s+=v; q+=v*v; }
      red[r][t] = s;
    }
    __syncthreads();
    if(tid<4){ float ss=0; for(int i=0;i<64;++i) ss+=red[tid][i]; mu4[tid]=ss*(1.f/512.f); }
    __syncthreads();
    if(tid<256) red[r][t] = q;
    __syncthreads();
    if(tid<4){ float qq=0; for(int i=0;i<64;++i) qq+=red[tid][i];
      float m=mu4[tid]; rs4[tid]=1.f/sqrtf(fmaxf(qq*(1.f/512.f)-m*m,0.f)+1e-5f); }
    __syncthreads();
  }
  for(int e=tid; e<2048; e+=512){ int r=e>>9, d=e&511;
    xl[r][d] = (xs[r][d]-mu4[r])*rs4[r]*g1[d] + b1p[d]; }
  __syncthreads();
  int d=tid;
  float ak[4], av[4];
  float bk=ipb[512+d], bv=ipb[1024+d];
  #pragma unroll
  for(int r=0;r<4;++r){ ak[r]=bk; av[r]=bv; }
  for(int din=0; din<512; din+=4){
    float wk[4], wv[4];
    #pragma unroll
    for(int u=0;u<4;++u){ wk[u]=WT[(din+u)*1536+512+d]; wv[u]=WT[(din+u)*1536+1024+d]; }
    #pragma unroll
    for(int r=0;r<4;++r){
      float4 a4 = *(const float4*)&xl[r][din];
      float4 x4 = *(const float4*)&xs[r][din];
      ak[r] += a4.x*wk[0]+a4.y*wk[1]+a4.z*wk[2]+a4.w*wk[3];
      av[r] += x4.x*wv[0]+x4.y*wv[1]+x4.z*wv[2]+x4.w*wv[3];
    }
  }
  #pragma unroll
  for(int r=0;r<4;++r){
    size_t base = (size_t)(r0+r)*512;
    kmat[base+d]=ak[r]; vmat[base+d]=av[r];
  }
}

// ---------------- K3: scores + softmax (640 blocks: kc x b x h) ----------------
__global__ __launch_bounds__(256) void k3_attn(const float* qws, const float* kmat, float* attf){
  int bid = blockIdx.x;
  int kc = bid>>6, b = (bid>>3)&7, h = bid&7;
  int tid = threadIdx.x; int n = tid; int w = tid>>6, ln = tid&63;
  __shared__ float qb[8][64];
  __shared__ float rM[8][4], rS[8][4];
  float4 kr[16];
  if(n < 196){
    const float4* kp = (const float4*)(kmat + ((size_t)(b*196+n))*512 + h*64);
    #pragma unroll
    for(int j=0;j<16;++j) kr[j] = kp[j];
  }
  int kbase = kc*8;
  for(int e=tid; e<512; e+=256){ int kk=e>>6, j=e&63; int k=kbase+kk;
    qb[kk][j] = (k<77)? qws[k*512 + h*64 + j] : 0.f; }
  __syncthreads();
  float sc[8];
  #pragma unroll
  for(int kk=0;kk<8;++kk){
    float s = 0.f;
    if(n<196){
      const float4* q4 = (const float4*)qb[kk];
      #pragma unroll
      for(int j=0;j<16;++j){ float4 q = q4[j];
        s += q.x*kr[j].x + q.y*kr[j].y + q.z*kr[j].z + q.w*kr[j].w; }
      sc[kk] = s*0.125f;
    } else sc[kk] = -INFINITY;
  }
  #pragma unroll
  for(int kk=0;kk<8;++kk){ float m = wmaxf(sc[kk]); if(!ln) rM[kk][w]=m; }
  __syncthreads();
  float ex[8];
  #pragma unroll
  for(int kk=0;kk<8;++kk){
    float m = fmaxf(fmaxf(rM[kk][0],rM[kk][1]),fmaxf(rM[kk][2],rM[kk][3]));
    float e = expf(sc[kk]-m);
    ex[kk]=e;
    float s = wsumf(e); if(!ln) rS[kk][w]=s;
  }
  __syncthreads();
  #pragma unroll
  for(int kk=0;kk<8;++kk){
    int k = kbase+kk;
    if(k<77 && n<196){
      float tot = rS[kk][0]+rS[kk][1]+rS[kk][2]+rS[kk][3];
      attf[(((size_t)(b*8+h))*77 + k)*196 + n] = ex[kk]/tot;
    }
  }
}

// ---------------- K4: ctx = attn @ v (640 blocks: kc x b x h) ----------------
__global__ __launch_bounds__(256) void k4_ctx(const float* attf, const float* vmat, float* ctx){
  int bid = blockIdx.x;
  int kc = bid>>6, b = (bid>>3)&7, h = bid&7;
  int tid = threadIdx.x; int ng = tid>>6, j = tid&63;
  __shared__ float vT[196][64];
  __shared__ float aT[8][196];
  __shared__ float red[8][4][64];
  for(int e=tid; e<196*16; e+=256){ int n=e>>4, jc=e&15;
    const float4* vp = (const float4*)(vmat + ((size_t)(b*196+n))*512 + h*64);
    *(float4*)&vT[n][jc*4] = vp[jc];
  }
  int kbase=kc*8;
  for(int e=tid; e<8*196; e+=256){ int kk=e/196, n=e-kk*196; int k=kbase+kk;
    aT[kk][n] = (k<77)? attf[(((size_t)(b*8+h))*77+k)*196+n] : 0.f; }
  __syncthreads();
  float vr[49];
  #pragma unroll
  for(int t=0;t<49;++t) vr[t] = vT[ng*49+t][j];
  #pragma unroll
  for(int kk=0;kk<8;++kk){
    float p=0.f;
    #pragma unroll
    for(int t=0;t<49;++t) p += aT[kk][ng*49+t]*vr[t];
    red[kk][ng][j]=p;
  }
  __syncthreads();
  for(int e=tid; e<512; e+=256){ int kk=e>>6, j2=e&63; int k=kbase+kk;
    if(k<77){
      float s = red[kk][0][j2]+red[kk][1][j2]+red[kk][2][j2]+red[kk][3][j2];
      ctx[((size_t)(b*77+k))*512 + h*64 + j2] = s;
    } }
}

// ---------------- K5: attn_weights = mean over H ----------------
__global__ void k5_attw(const float* attf, float* attw, float* out2){
  int idx = blockIdx.x*256+threadIdx.x;
  if(idx >= 8*77*196) return;
  int b = idx / (77*196); int rem = idx - b*(77*196);
  float s=0.f;
  #pragma unroll
  for(int h=0;h<8;++h) s += attf[((size_t)(b*8+h))*77*196 + rem];
  s *= 0.125f;
  attw[idx]=s; out2[idx]=s;
}

// ---------------- K6: AO = LN2(ctx @ out_w^T + out_b)  (4 rows/block, 154 blocks) ----
__global__ __launch_bounds__(512) void k6_ao(const float* ctx, const float* OWT,
                                             const float* ob, const float* g2, const float* b2p,
                                             float* AO){
  int R0 = blockIdx.x*4; int tid = threadIdx.x;
  __shared__ float xs[4][512];
  __shared__ float ao[4][512];
  __shared__ float red[4][64];
  __shared__ float mu4[4], rs4[4];
  for(int e=tid;e<2048;e+=512){ int r=e>>9,d=e&511; xs[r][d]=ctx[(size_t)(R0+r)*512+d]; }
  __syncthreads();
  int d=tid;
  float a[4]; float obv=ob[d];
  #pragma unroll
  for(int r=0;r<4;++r) a[r]=obv;
  for(int din=0;din<512;din+=4){
    float wv[4];
    #pragma unroll
    for(int u=0;u<4;++u) wv[u]=OWT[(din+u)*512+d];
    #pragma unroll
    for(int r=0;r<4;++r){
      float4 x4 = *(const float4*)&xs[r][din];
      a[r] += x4.x*wv[0]+x4.y*wv[1]+x4.z*wv[2]+x4.w*wv[3];
    }
  }
  #pragma unroll
  for(int r=0;r<4;++r) ao[r][d]=a[r];
  __syncthreads();
  {
    float s=0.f,q=0.f; int r=0,t=0;
    if(tid<256){
      r=tid>>6; t=tid&63;
      for(int i=0;i<8;++i){ float v=ao[r][t+64*i]; s+=v; q+=v*v; }
      red[r][t]=s;
    }
    __syncthreads();
    if(tid<4){ float ss=0; for(int i=0;i<64;++i) ss+=red[tid][i]; mu4[tid]=ss*(1.f/512.f); }
    __syncthreads();
    if(tid<256) red[r][t]=q;
    __syncthreads();
    if(tid<4){ float qq=0; for(int i=0;i<64;++i) qq+=red[tid][i];
      float m=mu4[tid]; rs4[tid]=1.f/sqrtf(fmaxf(qq*(1.f/512.f)-m*m,0.f)+1e-5f); }
    __syncthreads();
  }
  for(int e=tid;e<2048;e+=512){ int r=e>>9,dd=e&511;
    AO[(size_t)(R0+r)*512+dd] = (ao[r][dd]-mu4[r])*rs4[r]*g2[dd] + b2p[dd]; }
}

// ---------------- K6b: Sv = (1/77) attw^T @ AO per (b, 8-n tile); wsum ---------
__global__ __launch_bounds__(512) void k6b_sv(const float* AO, const float* attw,
                                              float* Svws, float* wsumws){
  int bid = blockIdx.x;
  int b = bid/25, nt = bid - b*25;
  int n0 = nt*8;
  int tid = threadIdx.x;
  __shared__ float wsK[80][8];
  for(int e=tid; e<640; e+=512){ int k=e>>3, r=e&7; int n=n0+r;
    wsK[k][r] = (k<77 && n<196)? attw[((size_t)(b*77+k))*196 + n] : 0.f; }
  __syncthreads();
  if(tid<8){ int n=n0+tid;
    if(n<196){ float s=0.f;
      for(int k=0;k<77;++k) s+=wsK[k][tid];
      wsumws[b*196+n]=s; } }
  int d = tid;
  float acc[8];
  #pragma unroll
  for(int r=0;r<8;++r) acc[r]=0.f;
  const float* aob = AO + (size_t)b*77*512 + d;
  for(int k=0;k<77;++k){
    float a = aob[(size_t)k*512];
    #pragma unroll
    for(int r=0;r<8;++r) acc[r] += wsK[k][r]*a;
  }
  #pragma unroll
  for(int r=0;r<8;++r){ int n=n0+r; if(n<196)
    Svws[((size_t)(b*196+n))*512 + d] = acc[r]*(1.f/77.f); }
}

// ---------------- K7: per-(b,n,third) fused MLP; A LDS-resident, barrier-free t-loop
// 3-way row split: thirds (MT=2,2,1). A-LDS 64KB (MT=2), struct 77.6KB ->
// 2 blocks/CU -> unified reg budget per wave: arch + 32 AGPR <= 128.
// t-loop: 2-Bset ping-pong (R12/R14-proven), ds_read A, MFMA, zero barriers.
// B-traffic model (R15 lesson): time ~= blocks x 1MB / 18TB/s; 32 rows/block
// is the LDS max at 2 blk/CU -> ~261us floor. Depth-2 prefetch and >2 chunks
// per bn both REGRESSED - don't reintroduce.
// A-LDS permutation: pos = (P+t)&63 with P=((ln&15)<<2)|(ln>>4): bank residue
// (4r+k8+t)%8 is uniform across the wave for BOTH stage-writes and reads.
struct __align__(16) K7Smem {
  _Float16 Ah[2*16*512];    // [mt][t][pos 0..63][8], pos=(P(lane)+t)&63
  _Float16 Al[2*16*512];
  float b1s[512], gs[512], bs[512];
  float wvS[80];
  float redS[8][32], redQ[8][32];
  float muA[32], rsA[32];
  float gfin[512];
  float qred[320];
};   // 77.6 KB -> 2 blocks/CU

#define K7_MFMA3(ACC, AFH, AFL, BH, BL) \
  ACC = __builtin_amdgcn_mfma_f32_16x16x32_f16(AFL, BH, ACC, 0,0,0); \
  ACC = __builtin_amdgcn_mfma_f32_16x16x32_f16(AFH, BL, ACC, 0,0,0); \
  ACC = __builtin_amdgcn_mfma_f32_16x16x32_f16(AFH, BH, ACC, 0,0,0);

struct Bset { f16x8 h0,h1,h2,h3,l0,l1,l2,l3; };

DI void loadB(Bset& s, const _Float16* bph, const _Float16* bpl, int t){
  const _Float16* ph = bph + t*16384;
  const _Float16* pl = bpl + t*16384;
  s.h0 = *(const f16x8*)(ph);       s.h1 = *(const f16x8*)(ph+512);
  s.h2 = *(const f16x8*)(ph+1024);  s.h3 = *(const f16x8*)(ph+1536);
  s.l0 = *(const f16x8*)(pl);       s.l1 = *(const f16x8*)(pl+512);
  s.l2 = *(const f16x8*)(pl+1024);  s.l3 = *(const f16x8*)(pl+1536);
}

template<int MT>
DI void stepMFMA(f32x4 acc[][4], const _Float16* Ah, const _Float16* Al,
                 const Bset& B, int t, int lp){
  #pragma unroll
  for(int mt=0; mt<MT; ++mt){
    int off = (mt*16 + t)*512 + ((lp + t)&63)*8;
    f16x8 fh = *(const f16x8*)&Ah[off];
    f16x8 fl = *(const f16x8*)&Al[off];
    K7_MFMA3(acc[mt][0], fh, fl, B.h0, B.l0)
    K7_MFMA3(acc[mt][1], fh, fl, B.h1, B.l1)
    K7_MFMA3(acc[mt][2], fh, fl, B.h2, B.l2)
    K7_MFMA3(acc[mt][3], fh, fl, B.h3, B.l3)
  }
}

template<int MT, int K0>
DI void k7_body(int bn, const float* F, const float* AO, const float* attw,
                const _Float16* w1hi, const _Float16* w1lo,
                const float* b1p, const float* lng, const float* lnb,
                const float* w2, const float* b2p,
                const float* Svws, const float* wsumws,
                float* Qpws, K7Smem& sm){
  int b = bn/196, n = bn - b*196;
  int tid = threadIdx.x; int w = tid>>6, ln = tid&63;
  int col = ln&15, quad = ln>>4;
  const float* AObase = AO + (size_t)b*77*512;
  sm.b1s[tid] = b1p[tid]; sm.gs[tid] = lng[tid]; sm.bs[tid] = lnb[tid];
  if(tid<80) sm.wvS[tid] = (tid<77)? attw[((size_t)(b*77+tid))*196+n] : 0.f;
  __syncthreads();

  // ---- stage clean (hi/lo) for MT*16 rows into LDS; this thread owns fixed d0
  {
    int d0 = (tid&63)*8;            // fixed k-slice for this thread
    int r0 = tid>>6;                // base row 0..7 (+8 per step)
    int t  = d0>>5;
    int k8 = (d0&31)>>3;
    float4 f0 = *(const float4*)&F[(size_t)bn*512 + d0];
    float4 f1 = *(const float4*)&F[(size_t)bn*512 + d0+4];
    float4 sv0 = *(const float4*)&Svws[(size_t)bn*512 + d0];
    float4 sv1 = *(const float4*)&Svws[(size_t)bn*512 + d0+4];
    float fk[8] = {f0.x*1024.f,f0.y*1024.f,f0.z*1024.f,f0.w*1024.f,
                   f1.x*1024.f,f1.y*1024.f,f1.z*1024.f,f1.w*1024.f};
    float sv[8] = {sv0.x,sv0.y,sv0.z,sv0.w,sv1.x,sv1.y,sv1.z,sv1.w};
    #pragma unroll
    for(int it=0; it<MT*2; ++it){
      int row = r0 + it*8;          // local row 0..MT*16-1
      int grow = K0 + row;
      bool ok = grow < 77;
      int rl = ok ? grow : 0;
      float wm = ok ? sm.wvS[grow] : 0.f;
      const float* ap = AObase + (size_t)rl*512 + d0;
      float4 a0 = *(const float4*)ap;
      float4 a1 = *(const float4*)(ap+4);
      float av[8] = {a0.x,a0.y,a0.z,a0.w,a1.x,a1.y,a1.z,a1.w};
      f16x8 hfrag, lfrag;
      #pragma unroll
      for(int i=0;i<8;++i){
        float c = ok ? fk[i]*(wm*av[i] - sv[i]) : 0.f;
        _Float16 h = (_Float16)c;
        hfrag[i] = h;
        lfrag[i] = (_Float16)(c - (float)h);
      }
      // P(lane) = ((lane&15)<<2)|(lane>>4) with lane=(row&15)|(k8<<4)
      int P = ((row&15)<<2) | k8;
      int pos = (P + t)&63;
      int idx = (((row>>4)*16 + t)*512) + pos*8;
      *(f16x8*)&sm.Ah[idx] = hfrag;
      *(f16x8*)&sm.Al[idx] = lfrag;
    }
  }
  __syncthreads();
  // ---- barrier-free t-loop: A from LDS, B 2-set ping-pong from global ----
  f32x4 acc[MT][4];
  #pragma unroll
  for(int mt=0;mt<MT;++mt)
    #pragma unroll
    for(int jj=0;jj<4;++jj) acc[mt][jj] = (f32x4){0.f,0.f,0.f,0.f};

  const _Float16* bph = w1hi + ((w*4)*64 + ln)*8;  // +512 per jj, +16384 per t
  const _Float16* bpl = w1lo + ((w*4)*64 + ln)*8;
  int lp = ((ln&15)<<2) | (ln>>4);                 // per-thread A-read permutation

  Bset s0, s1;
  loadB(s0, bph, bpl, 0);
  #pragma unroll 1
  for(int tt=0; tt<16; tt+=2){
    loadB(s1, bph, bpl, tt+1);                 // prefetch odd step
    stepMFMA<MT>(acc, sm.Ah, sm.Al, s0, tt, lp);
    if(tt+2<16) loadB(s0, bph, bpl, tt+2);     // prefetch next even step
    stepMFMA<MT>(acc, sm.Ah, sm.Al, s1, tt+1, lp);
  }

  const float UNS = 1.f/65536.f;
  #pragma unroll
  for(int mt=0;mt<MT;++mt){
    float s[4]={0.f,0.f,0.f,0.f}, q[4]={0.f,0.f,0.f,0.f};
    #pragma unroll
    for(int jj=0;jj<4;++jj){
      int j = w*64 + jj*16 + col; float bj = sm.b1s[j];
      #pragma unroll
      for(int r=0;r<4;++r){
        float h = acc[mt][jj][r]*UNS + bj;
        s[r]+=h; q[r]+=h*h;
      }
    }
    #pragma unroll
    for(int r=0;r<4;++r){
      #pragma unroll
      for(int o=1;o<16;o<<=1){ s[r]+=__shfl_xor(s[r],o,64); q[r]+=__shfl_xor(q[r],o,64); }
    }
    if(col==0){
      #pragma unroll
      for(int r=0;r<4;++r){ int row = mt*16+quad*4+r; sm.redS[w][row]=s[r]; sm.redQ[w][row]=q[r]; }
    }
  }
  __syncthreads();
  if(tid<MT*16){
    float s=0.f,q=0.f;
    #pragma unroll
    for(int ww=0;ww<8;++ww){ s+=sm.redS[ww][tid]; q+=sm.redQ[ww][tid]; }
    float mu = s*(1.f/512.f);
    float var = q*(1.f/512.f)-mu*mu;
    sm.muA[tid]=mu; sm.rsA[tid]=1.f/sqrtf(fmaxf(var,0.f)+1e-5f);
  }
  __syncthreads();
  float gp[4]={0.f,0.f,0.f,0.f};
  #pragma unroll
  for(int mt=0;mt<MT;++mt){
    #pragma unroll
    for(int r=0;r<4;++r){
      int lr = mt*16+quad*4+r;
      float mu=sm.muA[lr], rs=sm.rsA[lr], wk=sm.wvS[K0+lr];
      #pragma unroll
      for(int jj=0;jj<4;++jj){
        int j = w*64 + jj*16 + col;
        float h = acc[mt][jj][r]*UNS + sm.b1s[j];
        float x = (h-mu)*rs;
        float y = x*sm.gs[j]+sm.bs[j];
        float gl = 0.5f*y*(1.f+erff(y*0.70710678118654752f));
        gp[jj] += wk*gl;
      }
    }
  }
  #pragma unroll
  for(int jj=0;jj<4;++jj){ gp[jj]+=__shfl_xor(gp[jj],16,64); gp[jj]+=__shfl_xor(gp[jj],32,64); }
  if(ln<16){
    #pragma unroll
    for(int jj=0;jj<4;++jj) sm.gfin[w*64 + jj*16 + ln] = gp[jj];
  }
  __syncthreads();
  if(tid<320){ int m=tid>>4, seg=tid&15; float p=0.f;
    for(int u=0;u<32;++u){ int uu=(u+seg)&31; int j=seg*32+uu;   // rotated: per-lane distinct banks
      p += sm.gfin[j]*w2[m*512+j]; }
    sm.qred[m*16+seg]=p; }
  __syncthreads();
  if(tid<20){ float s=0.f;
    for(int seg=0;seg<16;++seg) s+=sm.qred[tid*16+seg];
    if(K0==0) s += b2p[tid]*wsumws[bn];          // bias term once, in third 0
    Qpws[(size_t)bn*60 + (K0==0?0:(K0==32?20:40)) + tid]=s; }
}

__global__
__attribute__((amdgpu_flat_work_group_size(512,512)))
void k7_mlp(const float* F, const float* AO, const float* attw,
            const _Float16* w1hi, const _Float16* w1lo,
            const float* b1p, const float* lng, const float* lnb,
            const float* w2, const float* b2p,
            const float* Svws, const float* wsumws,
            float* Qpws){
  __shared__ K7Smem sm;
  int bid = blockIdx.x;
  int bn = bid/3;
  int third = bid - bn*3;
  if(third==0)      k7_body<2,0 >(bn,F,AO,attw,w1hi,w1lo,b1p,lng,lnb,w2,b2p,Svws,wsumws,Qpws,sm);
  else if(third==1) k7_body<2,32>(bn,F,AO,attw,w1hi,w1lo,b1p,lng,lnb,w2,b2p,Svws,wsumws,Qpws,sm);
  else              k7_body<1,64>(bn,F,AO,attw,w1hi,w1lo,b1p,lng,lnb,w2,b2p,Svws,wsumws,Qpws,sm);
}

// ---------------- K8: per-(b,n) top-51 mask + normalize -> out1 ----------------
__global__ __launch_bounds__(256) void k8_topk(const float* F, const float* T,
                                               const float* Qpws, float* out1){
  int bn = blockIdx.x; int tid = threadIdx.x;
  int w = tid>>6, ln = tid&63;
  __shared__ float Fv[512];
  __shared__ float QpS[20];
  __shared__ float ninv[20];
  __shared__ unsigned char selb[20][64];
  for(int e=tid;e<512;e+=256) Fv[e]=F[(size_t)bn*512+e];
  if(tid<20) QpS[tid]=Qpws[(size_t)bn*60+tid] + Qpws[(size_t)bn*60+20+tid] + Qpws[(size_t)bn*60+40+tid];
  __syncthreads();
  for(int rr=0; rr<5; ++rr){
    int m = rr*4 + w;
    float qv[8]; uint key[8];
    const float4* tp = (const float4*)(T + (size_t)m*512 + ln*8);
    float4 t0 = tp[0], t1 = tp[1];
    float tf[8] = {t0.x,t0.y,t0.z,t0.w,t1.x,t1.y,t1.z,t1.w};
    float qp = QpS[m];
    #pragma unroll
    for(int i=0;i<8;++i){ float p = Fv[ln*8+i]*tf[i]; qv[i]=p*qp;
      key[i]=__float_as_uint(qv[i])&0x7fffffffu; }
    uint th=0u;
    for(int bit=30; bit>=0; --bit){
      uint cand = th | (1u<<bit);
      int c=0;
      #pragma unroll
      for(int i=0;i<8;++i) c += (int)__popcll(__ballot(key[i]>=cand));
      if(c>=51) th=cand;
    }
    int cg=0;
    #pragma unroll
    for(int i=0;i<8;++i) cg += (int)__popcll(__ballot(key[i]>th));
    int rneed = 51-cg;
    int eqc=0;
    #pragma unroll
    for(int i=0;i<8;++i) eqc += (key[i]==th);
    int pre=eqc;
    for(int o=1;o<64;o<<=1){ int v=__shfl_up(pre,o,64); if(ln>=o) pre+=v; }
    pre -= eqc;
    unsigned char mbits=0; float ss=0.f; int rk=pre;
    #pragma unroll
    for(int i=0;i<8;++i){
      bool s;
      if(key[i]>th) s=true;
      else if(key[i]==th){ s = (rk<rneed); rk++; }
      else s=false;
      if(s){ mbits |= (unsigned char)(1u<<i); ss += qv[i]*qv[i]; }
    }
    ss = wsumf(ss);
    if(ln==0) ninv[m] = 1.f/fmaxf(sqrtf(ss),1e-6f);
    selb[m][ln]=mbits;
  }
  __syncthreads();
  size_t base=(size_t)bn*10240;
  for(int e=tid;e<10240;e+=256){
    int d=e/20, mm=e-d*20;
    float val=0.f;
    if((selb[mm][d>>3]>>(d&7))&1){
      val = Fv[d]*T[(size_t)mm*512+d]*QpS[mm]*ninv[mm];
    }
    out1[base+e]=val;
  }
}

extern "C" void kernel_launch(void* const* d_in, const int* in_sizes, int n_in,
                              void* d_out, int out_size, void* d_ws, size_t ws_size,
                              hipStream_t stream){
  const float* F    = (const float*)d_in[0];
  const float* text = (const float*)d_in[1];
  const float* ipw  = (const float*)d_in[2];
  const float* ipb  = (const float*)d_in[3];
  const float* outw = (const float*)d_in[4];
  const float* outb = (const float*)d_in[5];
  const float* g1   = (const float*)d_in[6];
  const float* b1   = (const float*)d_in[7];
  const float* g2   = (const float*)d_in[8];
  const float* b2   = (const float*)d_in[9];
  const float* mw1  = (const float*)d_in[10];
  const float* mb1  = (const float*)d_in[11];
  const float* mlg  = (const float*)d_in[12];
  const float* mlb  = (const float*)d_in[13];
  const float* mw2  = (const float*)d_in[14];
  const float* mb2  = (const float*)d_in[15];
  const float* tmpl = (const float*)d_in[16];
  float* ws = (float*)d_ws;
  float* WT   = ws;
  float* OWT  = ws +  786432;
  float* qws  = ws + 1048576;
  float* kmat = ws + 1088000;
  float* vmat = ws + 1890816;
  float* attf = ws + 2693632;
  float* attw = ws + 3659520;
  float* ctx  = ws + 3780256;
  float* AO   = ws + 4095648;
  _Float16* w1hi = (_Float16*)(ws + 4473760);
  _Float16* w1lo = (_Float16*)(ws + 4604832);
  // dead-region reuse:
  float* wsum = ws + 1048576;   // old qws region (dead after k3)
  float* Sv   = ws + 1088000;   // old kmat region (dead after k3, exact fit)
  float* Qp   = ws +  786432;   // old OWT region (dead after k6; 94080 fl <= 262144)
  float* out1 = (float*)d_out;
  float* out2 = out1 + 16056320;

  hipLaunchKernelGGL(k0_transpose, dim3(2048), dim3(256), 0, stream, ipw, outw, mw1, WT, OWT, w1hi, w1lo);
  hipLaunchKernelGGL(k1_q,   dim3(154), dim3(256), 0, stream, text, ipb, g1, b1, WT, qws);
  hipLaunchKernelGGL(k2_kv,  dim3(392), dim3(512), 0, stream, F, ipb, g1, b1, WT, kmat, vmat);
  hipLaunchKernelGGL(k3_attn,dim3(640), dim3(256), 0, stream, qws, kmat, attf);
  hipLaunchKernelGGL(k4_ctx, dim3(640), dim3(256), 0, stream, attf, vmat, ctx);
  hipLaunchKernelGGL(k5_attw,dim3(472), dim3(256), 0, stream, attf, attw, out2);
  hipLaunchKernelGGL(k6_ao,  dim3(154), dim3(512), 0, stream, ctx, OWT, outb, g2, b2, AO);
  hipLaunchKernelGGL(k6b_sv, dim3(200), dim3(512), 0, stream, AO, attw, Sv, wsum);
  hipLaunchKernelGGL(k7_mlp, dim3(4704),dim3(512), 0, stream, F, AO, attw, w1hi, w1lo, mb1, mlg, mlb, mw2, mb2, Sv, wsum, Qp);
  hipLaunchKernelGGL(k8_topk,dim3(1568),dim3(256), 0, stream, F, tmpl, Qp, out1);
}

// Round 11
// 579.390 us; speedup vs baseline: 1.2255x; 1.0486x over previous
//
#include <hip/hip_runtime.h>
#include <hip/hip_bf16.h>
#include <math.h>

// B=8 N=196 D=512 M=20 K=77 H=8 hd=64, keep=51.  All inputs/outputs fp32.
// out1 = Qs/nrm (B,N,D,M) 16,056,320 fl; out2 = attn_weights (B,K,N) 120,736 fl
// Workspace layout: see kernel_launch. Dead-region reuse:
//   wsum -> qws (@1048576, dead after k3), Sv -> kmat (@1088000, dead after k3),
//   Qp -> OWT (@786432, 156800 fl <= 262144, dead after k6).
//
// R17 (from R16: total 607us best; k7 294us tracks B-traffic/18TB/s; R16's
// P-permutation RAISED conflicts 6.1->10.1M -> reverted to (lane+t)&63):
//  k7 batches 2 bn per block: 5 chunks x 16 rows x 2 bn. A-LDS stays 64KB,
//  struct 81.3KB (+192 pad < 81920) -> still 2 blk/CU; blocks 4704->3920 ->
//  B-traffic 4.7->3.92GB (-17%). LN is per-row so shared reduce arrays are
//  safe; gp/gfin/qred/Qp split per sub. acc[2][4]=32 AGPR (budget rule OK).

typedef unsigned int uint;
typedef _Float16 f16x8 __attribute__((ext_vector_type(8)));
typedef float f32x4 __attribute__((ext_vector_type(4)));

#define DI __device__ __forceinline__

DI float wsumf(float v){ for(int o=32;o>0;o>>=1) v += __shfl_xor(v,o,64); return v; }
DI int   wsumi(int v){ for(int o=32;o>0;o>>=1) v += __shfl_xor(v,o,64); return v; }
DI float wmaxf(float v){ for(int o=32;o>0;o>>=1) v = fmaxf(v,__shfl_xor(v,o,64)); return v; }

// ---------------- K0: tiled transposes + W1 split/swizzle ----------------
__global__ __launch_bounds__(256) void k0_transpose(const float* ipw, const float* ow, const float* mw1,
                             float* WT, float* OWT, _Float16* w1hi, _Float16* w1lo){
  int bid = blockIdx.x;
  if(bid < 768){
    __shared__ float t[32][33];
    int tdin = bid & 15, tdout = bid >> 4;
    int tx = threadIdx.x & 31, ty = threadIdx.x >> 5;
    int dout0 = tdout*32, din0 = tdin*32;
    for(int r=ty; r<32; r+=8) t[r][tx] = ipw[(size_t)(dout0+r)*512 + din0+tx];
    __syncthreads();
    for(int r=ty; r<32; r+=8) WT[(size_t)(din0+r)*1536 + dout0+tx] = t[tx][r];
  } else if(bid < 1024){
    __shared__ float t[32][33];
    int b2 = bid - 768;
    int tdin = b2 & 15, tdout = b2 >> 4;
    int tx = threadIdx.x & 31, ty = threadIdx.x >> 5;
    int dout0 = tdout*32, din0 = tdin*32;
    for(int r=ty; r<32; r+=8) t[r][tx] = ow[(size_t)(dout0+r)*512 + din0+tx];
    __syncthreads();
    for(int r=ty; r<32; r+=8) OWT[(size_t)(din0+r)*512 + dout0+tx] = t[tx][r];
  } else {
    int i3 = (bid-1024)*256 + threadIdx.x;
    int t = i3&7, ln = (i3>>3)&63, J = (i3>>9)&31, T = i3>>14;
    int j = J*16 + (ln&15);
    int d = T*32 + ((ln>>4)<<3) + t;
    float w = mw1[j*512 + d] * 64.0f;
    _Float16 hi = (_Float16)w;
    _Float16 lo = (_Float16)(w - (float)hi);
    w1hi[i3] = hi; w1lo[i3] = lo;
  }
}

// ---------------- K1: q = LN(text) @ Wq^T + bq  (154 blocks: k x half) ----------------
__global__ __launch_bounds__(256) void k1_q(const float* text, const float* ipb,
                                            const float* g1, const float* b1p,
                                            const float* WT, float* qws){
  int k = blockIdx.x >> 1, half = blockIdx.x & 1;
  int tid = threadIdx.x;
  __shared__ float xln[512];
  __shared__ float rA[4], rB[4];
  float x0 = text[k*512+tid], x1 = text[k*512+256+tid];
  float s1 = wsumf(x0+x1), s2 = wsumf(x0*x0+x1*x1);
  int w = tid>>6, ln = tid&63;
  if(!ln){ rA[w]=s1; rB[w]=s2; }
  __syncthreads();
  float mu = (rA[0]+rA[1]+rA[2]+rA[3])*(1.f/512.f);
  float var = (rB[0]+rB[1]+rB[2]+rB[3])*(1.f/512.f) - mu*mu;
  float rs = 1.f/sqrtf(fmaxf(var,0.f) + 1e-5f);
  xln[tid]     = (x0-mu)*rs*g1[tid]     + b1p[tid];
  xln[tid+256] = (x1-mu)*rs*g1[tid+256] + b1p[tid+256];
  __syncthreads();
  int d = half*256 + tid;
  float a0=0.f,a1=0.f,a2=0.f,a3=0.f;   // 4 independent chains for ILP
  for(int din=0; din<512; din+=4){
    a0 += xln[din  ] * WT[(din  )*1536 + d];
    a1 += xln[din+1] * WT[(din+1)*1536 + d];
    a2 += xln[din+2] * WT[(din+2)*1536 + d];
    a3 += xln[din+3] * WT[(din+3)*1536 + d];
  }
  qws[k*512+d] = ipb[d] + ((a0+a1)+(a2+a3));
}

// ---------------- K2: k = LN(F)@Wk^T+bk, v = F@Wv^T+bv  (4 rows/block, 392 blocks) ----
__global__ __launch_bounds__(512) void k2_kv(const float* F, const float* ipb,
                                             const float* g1, const float* b1p,
                                             const float* WT, float* kmat, float* vmat){
  int r0 = blockIdx.x*4; int tid = threadIdx.x;
  __shared__ float xs[4][512];
  __shared__ float xl[4][512];
  __shared__ float red[4][64];
  __shared__ float mu4[4], rs4[4];
  for(int e=tid; e<2048; e+=512){ int r=e>>9, d=e&511; xs[r][d] = F[(size_t)(r0+r)*512 + d]; }
  __syncthreads();
  {
    float s=0.f, q=0.f; int r=0, t=0;
    if(tid<256){
      r = tid>>6; t = tid&63;
      for(int i=0;i<8;++i){ float v = xs[r][t+64*i]; s+=v; q+=v*v; }
      red[r][t] = s;
    }
    __syncthreads();
    if(tid<4){ float ss=0; for(int i=0;i<64;++i) ss+=red[tid][i]; mu4[tid]=ss*(1.f/512.f); }
    __syncthreads();
    if(tid<256) red[r][t] = q;
    __syncthreads();
    if(tid<4){ float qq=0; for(int i=0;i<64;++i) qq+=red[tid][i];
      float m=mu4[tid]; rs4[tid]=1.f/sqrtf(fmaxf(qq*(1.f/512.f)-m*m,0.f)+1e-5f); }
    __syncthreads();
  }
  for(int e=tid; e<2048; e+=512){ int r=e>>9, d=e&511;
    xl[r][d] = (xs[r][d]-mu4[r])*rs4[r]*g1[d] + b1p[d]; }
  __syncthreads();
  int d=tid;
  float ak[4], av[4];
  float bk=ipb[512+d], bv=ipb[1024+d];
  #pragma unroll
  for(int r=0;r<4;++r){ ak[r]=bk; av[r]=bv; }
  for(int din=0; din<512; din+=4){
    float wk[4], wv[4];
    #pragma unroll
    for(int u=0;u<4;++u){ wk[u]=WT[(din+u)*1536+512+d]; wv[u]=WT[(din+u)*1536+1024+d]; }
    #pragma unroll
    for(int r=0;r<4;++r){
      float4 a4 = *(const float4*)&xl[r][din];
      float4 x4 = *(const float4*)&xs[r][din];
      ak[r] += a4.x*wk[0]+a4.y*wk[1]+a4.z*wk[2]+a4.w*wk[3];
      av[r] += x4.x*wv[0]+x4.y*wv[1]+x4.z*wv[2]+x4.w*wv[3];
    }
  }
  #pragma unroll
  for(int r=0;r<4;++r){
    size_t base = (size_t)(r0+r)*512;
    kmat[base+d]=ak[r]; vmat[base+d]=av[r];
  }
}

// ---------------- K3: scores + softmax (640 blocks: kc x b x h) ----------------
__global__ __launch_bounds__(256) void k3_attn(const float* qws, const float* kmat, float* attf){
  int bid = blockIdx.x;
  int kc = bid>>6, b = (bid>>3)&7, h = bid&7;
  int tid = threadIdx.x; int n = tid; int w = tid>>6, ln = tid&63;
  __shared__ float qb[8][64];
  __shared__ float rM[8][4], rS[8][4];
  float4 kr[16];
  if(n < 196){
    const float4* kp = (const float4*)(kmat + ((size_t)(b*196+n))*512 + h*64);
    #pragma unroll
    for(int j=0;j<16;++j) kr[j] = kp[j];
  }
  int kbase = kc*8;
  for(int e=tid; e<512; e+=256){ int kk=e>>6, j=e&63; int k=kbase+kk;
    qb[kk][j] = (k<77)? qws[k*512 + h*64 + j] : 0.f; }
  __syncthreads();
  float sc[8];
  #pragma unroll
  for(int kk=0;kk<8;++kk){
    float s = 0.f;
    if(n<196){
      const float4* q4 = (const float4*)qb[kk];
      #pragma unroll
      for(int j=0;j<16;++j){ float4 q = q4[j];
        s += q.x*kr[j].x + q.y*kr[j].y + q.z*kr[j].z + q.w*kr[j].w; }
      sc[kk] = s*0.125f;
    } else sc[kk] = -INFINITY;
  }
  #pragma unroll
  for(int kk=0;kk<8;++kk){ float m = wmaxf(sc[kk]); if(!ln) rM[kk][w]=m; }
  __syncthreads();
  float ex[8];
  #pragma unroll
  for(int kk=0;kk<8;++kk){
    float m = fmaxf(fmaxf(rM[kk][0],rM[kk][1]),fmaxf(rM[kk][2],rM[kk][3]));
    float e = expf(sc[kk]-m);
    ex[kk]=e;
    float s = wsumf(e); if(!ln) rS[kk][w]=s;
  }
  __syncthreads();
  #pragma unroll
  for(int kk=0;kk<8;++kk){
    int k = kbase+kk;
    if(k<77 && n<196){
      float tot = rS[kk][0]+rS[kk][1]+rS[kk][2]+rS[kk][3];
      attf[(((size_t)(b*8+h))*77 + k)*196 + n] = ex[kk]/tot;
    }
  }
}

// ---------------- K4: ctx = attn @ v (640 blocks: kc x b x h) ----------------
__global__ __launch_bounds__(256) void k4_ctx(const float* attf, const float* vmat, float* ctx){
  int bid = blockIdx.x;
  int kc = bid>>6, b = (bid>>3)&7, h = bid&7;
  int tid = threadIdx.x; int ng = tid>>6, j = tid&63;
  __shared__ float vT[196][64];
  __shared__ float aT[8][196];
  __shared__ float red[8][4][64];
  for(int e=tid; e<196*16; e+=256){ int n=e>>4, jc=e&15;
    const float4* vp = (const float4*)(vmat + ((size_t)(b*196+n))*512 + h*64);
    *(float4*)&vT[n][jc*4] = vp[jc];
  }
  int kbase=kc*8;
  for(int e=tid; e<8*196; e+=256){ int kk=e/196, n=e-kk*196; int k=kbase+kk;
    aT[kk][n] = (k<77)? attf[(((size_t)(b*8+h))*77+k)*196+n] : 0.f; }
  __syncthreads();
  float vr[49];
  #pragma unroll
  for(int t=0;t<49;++t) vr[t] = vT[ng*49+t][j];
  #pragma unroll
  for(int kk=0;kk<8;++kk){
    float p=0.f;
    #pragma unroll
    for(int t=0;t<49;++t) p += aT[kk][ng*49+t]*vr[t];
    red[kk][ng][j]=p;
  }
  __syncthreads();
  for(int e=tid; e<512; e+=256){ int kk=e>>6, j2=e&63; int k=kbase+kk;
    if(k<77){
      float s = red[kk][0][j2]+red[kk][1][j2]+red[kk][2][j2]+red[kk][3][j2];
      ctx[((size_t)(b*77+k))*512 + h*64 + j2] = s;
    } }
}

// ---------------- K5: attn_weights = mean over H ----------------
__global__ void k5_attw(const float* attf, float* attw, float* out2){
  int idx = blockIdx.x*256+threadIdx.x;
  if(idx >= 8*77*196) return;
  int b = idx / (77*196); int rem = idx - b*(77*196);
  float s=0.f;
  #pragma unroll
  for(int h=0;h<8;++h) s += attf[((size_t)(b*8+h))*77*196 + rem];
  s *= 0.125f;
  attw[idx]=s; out2[idx]=s;
}

// ---------------- K6: AO = LN2(ctx @ out_w^T + out_b)  (4 rows/block, 154 blocks) ----
__global__ __launch_bounds__(512) void k6_ao(const float* ctx, const float* OWT,
                                             const float* ob, const float* g2, const float* b2p,
                                             float* AO){
  int R0 = blockIdx.x*4; int tid = threadIdx.x;
  __shared__ float xs[4][512];
  __shared__ float ao[4][512];
  __shared__ float red[4][64];
  __shared__ float mu4[4], rs4[4];
  for(int e=tid;e<2048;e+=512){ int r=e>>9,d=e&511; xs[r][d]=ctx[(size_t)(R0+r)*512+d]; }
  __syncthreads();
  int d=tid;
  float a[4]; float obv=ob[d];
  #pragma unroll
  for(int r=0;r<4;++r) a[r]=obv;
  for(int din=0;din<512;din+=4){
    float wv[4];
    #pragma unroll
    for(int u=0;u<4;++u) wv[u]=OWT[(din+u)*512+d];
    #pragma unroll
    for(int r=0;r<4;++r){
      float4 x4 = *(const float4*)&xs[r][din];
      a[r] += x4.x*wv[0]+x4.y*wv[1]+x4.z*wv[2]+x4.w*wv[3];
    }
  }
  #pragma unroll
  for(int r=0;r<4;++r) ao[r][d]=a[r];
  __syncthreads();
  {
    float s=0.f,q=0.f; int r=0,t=0;
    if(tid<256){
      r=tid>>6; t=tid&63;
      for(int i=0;i<8;++i){ float v=ao[r][t+64*i]; s+=v; q+=v*v; }
      red[r][t]=s;
    }
    __syncthreads();
    if(tid<4){ float ss=0; for(int i=0;i<64;++i) ss+=red[tid][i]; mu4[tid]=ss*(1.f/512.f); }
    __syncthreads();
    if(tid<256) red[r][t]=q;
    __syncthreads();
    if(tid<4){ float qq=0; for(int i=0;i<64;++i) qq+=red[tid][i];
      float m=mu4[tid]; rs4[tid]=1.f/sqrtf(fmaxf(qq*(1.f/512.f)-m*m,0.f)+1e-5f); }
    __syncthreads();
  }
  for(int e=tid;e<2048;e+=512){ int r=e>>9,dd=e&511;
    AO[(size_t)(R0+r)*512+dd] = (ao[r][dd]-mu4[r])*rs4[r]*g2[dd] + b2p[dd]; }
}

// ---------------- K6b: Sv = (1/77) attw^T @ AO per (b, 8-n tile); wsum ---------
__global__ __launch_bounds__(512) void k6b_sv(const float* AO, const float* attw,
                                              float* Svws, float* wsumws){
  int bid = blockIdx.x;
  int b = bid/25, nt = bid - b*25;
  int n0 = nt*8;
  int tid = threadIdx.x;
  __shared__ float wsK[80][8];
  for(int e=tid; e<640; e+=512){ int k=e>>3, r=e&7; int n=n0+r;
    wsK[k][r] = (k<77 && n<196)? attw[((size_t)(b*77+k))*196 + n] : 0.f; }
  __syncthreads();
  if(tid<8){ int n=n0+tid;
    if(n<196){ float s=0.f;
      for(int k=0;k<77;++k) s+=wsK[k][tid];
      wsumws[b*196+n]=s; } }
  int d = tid;
  float acc[8];
  #pragma unroll
  for(int r=0;r<8;++r) acc[r]=0.f;
  const float* aob = AO + (size_t)b*77*512 + d;
  for(int k=0;k<77;++k){
    float a = aob[(size_t)k*512];
    #pragma unroll
    for(int r=0;r<8;++r) acc[r] += wsK[k][r]*a;
  }
  #pragma unroll
  for(int r=0;r<8;++r){ int n=n0+r; if(n<196)
    Svws[((size_t)(b*196+n))*512 + d] = acc[r]*(1.f/77.f); }
}

// ---------------- K7: per-(bn-pair, chunk) fused MLP; 2-bn batched, barrier-free t-loop
// 5 chunks x 16 rows x 2 bn per block. A-LDS 64KB, struct 81.3KB -> 2 blk/CU
// (R9/R11/R12-proven LDS-derived VGPR cap 128; acc 32 AGPR + ~70 arch fits).
// B-traffic: 3920 blocks x 1MB = 3.92GB (vs R16's 4.7GB). t-loop: 2-Bset
// ping-pong (proven), (lane+t)&63 A rotation (R16 P-perm raised conflicts ->
// reverted), zero barriers. LN per-row => shared reduce arrays safe; gp/gfin/
// qred/Qp are per-sub (per-bn).
struct __align__(16) K7Smem {
  _Float16 Ah[2*16*512];    // [sub][t][pos 0..63][8], pos=(lane+t)&63
  _Float16 Al[2*16*512];
  float b1s[512], gs[512], bs[512];
  float wvS[2][80];
  float redS[8][32], redQ[8][32];
  float muA[32], rsA[32];
  float gfin[2][512];
  float qred[2][320];
};   // 81280 B (+~192 runtime pad) < 81920 -> 2 blocks/CU

#define K7_MFMA3(ACC, AFH, AFL, BH, BL) \
  ACC = __builtin_amdgcn_mfma_f32_16x16x32_f16(AFL, BH, ACC, 0,0,0); \
  ACC = __builtin_amdgcn_mfma_f32_16x16x32_f16(AFH, BL, ACC, 0,0,0); \
  ACC = __builtin_amdgcn_mfma_f32_16x16x32_f16(AFH, BH, ACC, 0,0,0);

struct Bset { f16x8 h0,h1,h2,h3,l0,l1,l2,l3; };

DI void loadB(Bset& s, const _Float16* bph, const _Float16* bpl, int t){
  const _Float16* ph = bph + t*16384;
  const _Float16* pl = bpl + t*16384;
  s.h0 = *(const f16x8*)(ph);       s.h1 = *(const f16x8*)(ph+512);
  s.h2 = *(const f16x8*)(ph+1024);  s.h3 = *(const f16x8*)(ph+1536);
  s.l0 = *(const f16x8*)(pl);       s.l1 = *(const f16x8*)(pl+512);
  s.l2 = *(const f16x8*)(pl+1024);  s.l3 = *(const f16x8*)(pl+1536);
}

DI void stepMFMA2(f32x4 acc[2][4], const _Float16* Ah, const _Float16* Al,
                  const Bset& B, int t, int ln){
  #pragma unroll
  for(int s=0; s<2; ++s){
    int off = (s*16 + t)*512 + ((ln + t)&63)*8;
    f16x8 fh = *(const f16x8*)&Ah[off];
    f16x8 fl = *(const f16x8*)&Al[off];
    K7_MFMA3(acc[s][0], fh, fl, B.h0, B.l0)
    K7_MFMA3(acc[s][1], fh, fl, B.h1, B.l1)
    K7_MFMA3(acc[s][2], fh, fl, B.h2, B.l2)
    K7_MFMA3(acc[s][3], fh, fl, B.h3, B.l3)
  }
}

template<int K0>
DI void k7_body(int pair, const float* F, const float* AO, const float* attw,
                const _Float16* w1hi, const _Float16* w1lo,
                const float* b1p, const float* lng, const float* lnb,
                const float* w2, const float* b2p,
                const float* Svws, const float* wsumws,
                float* Qpws, K7Smem& sm){
  int bn0 = pair*2, bn1 = pair*2+1;
  int b0 = bn0/196, n0 = bn0 - b0*196;
  int b1c = bn1/196, n1 = bn1 - b1c*196;
  int tid = threadIdx.x; int w = tid>>6, ln = tid&63;
  int col = ln&15, quad = ln>>4;
  sm.b1s[tid] = b1p[tid]; sm.gs[tid] = lng[tid]; sm.bs[tid] = lnb[tid];
  if(tid<160){ int s = tid/80, k = tid - s*80;
    int bb = s? b1c:b0, nn = s? n1:n0;
    sm.wvS[s][k] = (k<77)? attw[((size_t)(bb*77+k))*196+nn] : 0.f; }
  __syncthreads();

  // ---- stage clean (hi/lo) for 16 rows x 2 bn into LDS; thread owns fixed d0
  {
    int d0 = (tid&63)*8;            // fixed k-slice for this thread
    int r0 = tid>>6;                // base row 0..7 (+8 on 2nd step)
    int t  = d0>>5;
    int k8 = (d0&31)>>3;
    #pragma unroll
    for(int s=0; s<2; ++s){
      int bn = s? bn1:bn0;
      const float* AObase = AO + (size_t)(s? b1c:b0)*77*512;
      float4 f0 = *(const float4*)&F[(size_t)bn*512 + d0];
      float4 f1 = *(const float4*)&F[(size_t)bn*512 + d0+4];
      float4 sv0 = *(const float4*)&Svws[(size_t)bn*512 + d0];
      float4 sv1 = *(const float4*)&Svws[(size_t)bn*512 + d0+4];
      float fk[8] = {f0.x*1024.f,f0.y*1024.f,f0.z*1024.f,f0.w*1024.f,
                     f1.x*1024.f,f1.y*1024.f,f1.z*1024.f,f1.w*1024.f};
      float sv[8] = {sv0.x,sv0.y,sv0.z,sv0.w,sv1.x,sv1.y,sv1.z,sv1.w};
      #pragma unroll
      for(int it=0; it<2; ++it){
        int row = r0 + it*8;        // local row 0..15
        int grow = K0 + row;
        bool ok = grow < 77;
        int rl = ok ? grow : 0;
        float wm = ok ? sm.wvS[s][grow] : 0.f;
        const float* ap = AObase + (size_t)rl*512 + d0;
        float4 a0 = *(const float4*)ap;
        float4 a1 = *(const float4*)(ap+4);
        float av[8] = {a0.x,a0.y,a0.z,a0.w,a1.x,a1.y,a1.z,a1.w};
        f16x8 hfrag, lfrag;
        #pragma unroll
        for(int i=0;i<8;++i){
          float c = ok ? fk[i]*(wm*av[i] - sv[i]) : 0.f;
          _Float16 h = (_Float16)c;
          hfrag[i] = h;
          lfrag[i] = (_Float16)(c - (float)h);
        }
        int lane = row | (k8<<4);   // row<16
        int pos = (lane + t)&63;
        int idx = ((s*16 + t)*512) + pos*8;
        *(f16x8*)&sm.Ah[idx] = hfrag;
        *(f16x8*)&sm.Al[idx] = lfrag;
      }
    }
  }
  __syncthreads();
  // ---- barrier-free t-loop: A from LDS, B 2-set ping-pong from global ----
  f32x4 acc[2][4];
  #pragma unroll
  for(int s=0;s<2;++s)
    #pragma unroll
    for(int jj=0;jj<4;++jj) acc[s][jj] = (f32x4){0.f,0.f,0.f,0.f};

  const _Float16* bph = w1hi + ((w*4)*64 + ln)*8;  // +512 per jj, +16384 per t
  const _Float16* bpl = w1lo + ((w*4)*64 + ln)*8;

  Bset s0, s1;
  loadB(s0, bph, bpl, 0);
  #pragma unroll 1
  for(int tt=0; tt<16; tt+=2){
    loadB(s1, bph, bpl, tt+1);                 // prefetch odd step
    stepMFMA2(acc, sm.Ah, sm.Al, s0, tt, ln);
    if(tt+2<16) loadB(s0, bph, bpl, tt+2);     // prefetch next even step
    stepMFMA2(acc, sm.Ah, sm.Al, s1, tt+1, ln);
  }

  const float UNS = 1.f/65536.f;
  #pragma unroll
  for(int s=0;s<2;++s){
    float sv4[4]={0.f,0.f,0.f,0.f}, q[4]={0.f,0.f,0.f,0.f};
    #pragma unroll
    for(int jj=0;jj<4;++jj){
      int j = w*64 + jj*16 + col; float bj = sm.b1s[j];
      #pragma unroll
      for(int r=0;r<4;++r){
        float h = acc[s][jj][r]*UNS + bj;
        sv4[r]+=h; q[r]+=h*h;
      }
    }
    #pragma unroll
    for(int r=0;r<4;++r){
      #pragma unroll
      for(int o=1;o<16;o<<=1){ sv4[r]+=__shfl_xor(sv4[r],o,64); q[r]+=__shfl_xor(q[r],o,64); }
    }
    if(col==0){
      #pragma unroll
      for(int r=0;r<4;++r){ int row = s*16+quad*4+r; sm.redS[w][row]=sv4[r]; sm.redQ[w][row]=q[r]; }
    }
  }
  __syncthreads();
  if(tid<32){
    float s=0.f,q=0.f;
    #pragma unroll
    for(int ww=0;ww<8;++ww){ s+=sm.redS[ww][tid]; q+=sm.redQ[ww][tid]; }
    float mu = s*(1.f/512.f);
    float var = q*(1.f/512.f)-mu*mu;
    sm.muA[tid]=mu; sm.rsA[tid]=1.f/sqrtf(fmaxf(var,0.f)+1e-5f);
  }
  __syncthreads();
  float gp[2][4] = {{0.f,0.f,0.f,0.f},{0.f,0.f,0.f,0.f}};
  #pragma unroll
  for(int s=0;s<2;++s){
    #pragma unroll
    for(int r=0;r<4;++r){
      int lr = quad*4+r;
      float mu=sm.muA[s*16+lr], rs=sm.rsA[s*16+lr], wk=sm.wvS[s][K0+lr];
      #pragma unroll
      for(int jj=0;jj<4;++jj){
        int j = w*64 + jj*16 + col;
        float h = acc[s][jj][r]*UNS + sm.b1s[j];
        float x = (h-mu)*rs;
        float y = x*sm.gs[j]+sm.bs[j];
        float gl = 0.5f*y*(1.f+erff(y*0.70710678118654752f));
        gp[s][jj] += wk*gl;
      }
    }
  }
  #pragma unroll
  for(int s=0;s<2;++s)
    #pragma unroll
    for(int jj=0;jj<4;++jj){ gp[s][jj]+=__shfl_xor(gp[s][jj],16,64); gp[s][jj]+=__shfl_xor(gp[s][jj],32,64); }
  if(ln<16){
    #pragma unroll
    for(int s=0;s<2;++s)
      #pragma unroll
      for(int jj=0;jj<4;++jj) sm.gfin[s][w*64 + jj*16 + ln] = gp[s][jj];
  }
  __syncthreads();
  for(int e=tid; e<640; e+=512){
    int s = e/320, rem = e - s*320;
    int m = rem>>4, seg = rem&15; float p=0.f;
    for(int u=0;u<32;++u){ int uu=(u+seg)&31; int j=seg*32+uu;   // rotated: per-lane distinct banks
      p += sm.gfin[s][j]*w2[m*512+j]; }
    sm.qred[s][m*16+seg]=p;
  }
  __syncthreads();
  if(tid<40){ int s=tid/20, m=tid-s*20; float acc2=0.f;
    for(int seg=0;seg<16;++seg) acc2+=sm.qred[s][m*16+seg];
    int bn = s? bn1:bn0;
    if(K0==0) acc2 += b2p[m]*wsumws[bn];         // bias term once, in chunk 0
    Qpws[(size_t)bn*100 + (K0>>4)*20 + m]=acc2; }
}

__global__
__attribute__((amdgpu_flat_work_group_size(512,512)))
void k7_mlp(const float* F, const float* AO, const float* attw,
            const _Float16* w1hi, const _Float16* w1lo,
            const float* b1p, const float* lng, const float* lnb,
            const float* w2, const float* b2p,
            const float* Svws, const float* wsumws,
            float* Qpws){
  __shared__ K7Smem sm;
  int bid = blockIdx.x;
  int pair = bid/5;
  int c = bid - pair*5;
  switch(c){
    case 0: k7_body<0 >(pair,F,AO,attw,w1hi,w1lo,b1p,lng,lnb,w2,b2p,Svws,wsumws,Qpws,sm); break;
    case 1: k7_body<16>(pair,F,AO,attw,w1hi,w1lo,b1p,lng,lnb,w2,b2p,Svws,wsumws,Qpws,sm); break;
    case 2: k7_body<32>(pair,F,AO,attw,w1hi,w1lo,b1p,lng,lnb,w2,b2p,Svws,wsumws,Qpws,sm); break;
    case 3: k7_body<48>(pair,F,AO,attw,w1hi,w1lo,b1p,lng,lnb,w2,b2p,Svws,wsumws,Qpws,sm); break;
    default:k7_body<64>(pair,F,AO,attw,w1hi,w1lo,b1p,lng,lnb,w2,b2p,Svws,wsumws,Qpws,sm); break;
  }
}

// ---------------- K8: per-(b,n) top-51 mask + normalize -> out1 ----------------
__global__ __launch_bounds__(256) void k8_topk(const float* F, const float* T,
                                               const float* Qpws, float* out1){
  int bn = blockIdx.x; int tid = threadIdx.x;
  int w = tid>>6, ln = tid&63;
  __shared__ float Fv[512];
  __shared__ float QpS[20];
  __shared__ float ninv[20];
  __shared__ unsigned char selb[20][64];
  for(int e=tid;e<512;e+=256) Fv[e]=F[(size_t)bn*512+e];
  if(tid<20){
    const float* qp = Qpws + (size_t)bn*100 + tid;
    QpS[tid] = qp[0]+qp[20]+qp[40]+qp[60]+qp[80];
  }
  __syncthreads();
  for(int rr=0; rr<5; ++rr){
    int m = rr*4 + w;
    float qv[8]; uint key[8];
    const float4* tp = (const float4*)(T + (size_t)m*512 + ln*8);
    float4 t0 = tp[0], t1 = tp[1];
    float tf[8] = {t0.x,t0.y,t0.z,t0.w,t1.x,t1.y,t1.z,t1.w};
    float qp = QpS[m];
    #pragma unroll
    for(int i=0;i<8;++i){ float p = Fv[ln*8+i]*tf[i]; qv[i]=p*qp;
      key[i]=__float_as_uint(qv[i])&0x7fffffffu; }
    uint th=0u;
    for(int bit=30; bit>=0; --bit){
      uint cand = th | (1u<<bit);
      int c=0;
      #pragma unroll
      for(int i=0;i<8;++i) c += (int)__popcll(__ballot(key[i]>=cand));
      if(c>=51) th=cand;
    }
    int cg=0;
    #pragma unroll
    for(int i=0;i<8;++i) cg += (int)__popcll(__ballot(key[i]>th));
    int rneed = 51-cg;
    int eqc=0;
    #pragma unroll
    for(int i=0;i<8;++i) eqc += (key[i]==th);
    int pre=eqc;
    for(int o=1;o<64;o<<=1){ int v=__shfl_up(pre,o,64); if(ln>=o) pre+=v; }
    pre -= eqc;
    unsigned char mbits=0; float ss=0.f; int rk=pre;
    #pragma unroll
    for(int i=0;i<8;++i){
      bool s;
      if(key[i]>th) s=true;
      else if(key[i]==th){ s = (rk<rneed); rk++; }
      else s=false;
      if(s){ mbits |= (unsigned char)(1u<<i); ss += qv[i]*qv[i]; }
    }
    ss = wsumf(ss);
    if(ln==0) ninv[m] = 1.f/fmaxf(sqrtf(ss),1e-6f);
    selb[m][ln]=mbits;
  }
  __syncthreads();
  size_t base=(size_t)bn*10240;
  for(int e=tid;e<10240;e+=256){
    int d=e/20, mm=e-d*20;
    float val=0.f;
    if((selb[mm][d>>3]>>(d&7))&1){
      val = Fv[d]*T[(size_t)mm*512+d]*QpS[mm]*ninv[mm];
    }
    out1[base+e]=val;
  }
}

extern "C" void kernel_launch(void* const* d_in, const int* in_sizes, int n_in,
                              void* d_out, int out_size, void* d_ws, size_t ws_size,
                              hipStream_t stream){
  const float* F    = (const float*)d_in[0];
  const float* text = (const float*)d_in[1];
  const float* ipw  = (const float*)d_in[2];
  const float* ipb  = (const float*)d_in[3];
  const float* outw = (const float*)d_in[4];
  const float* outb = (const float*)d_in[5];
  const float* g1   = (const float*)d_in[6];
  const float* b1   = (const float*)d_in[7];
  const float* g2   = (const float*)d_in[8];
  const float* b2   = (const float*)d_in[9];
  const float* mw1  = (const float*)d_in[10];
  const float* mb1  = (const float*)d_in[11];
  const float* mlg  = (const float*)d_in[12];
  const float* mlb  = (const float*)d_in[13];
  const float* mw2  = (const float*)d_in[14];
  const float* mb2  = (const float*)d_in[15];
  const float* tmpl = (const float*)d_in[16];
  float* ws = (float*)d_ws;
  float* WT   = ws;
  float* OWT  = ws +  786432;
  float* qws  = ws + 1048576;
  float* kmat = ws + 1088000;
  float* vmat = ws + 1890816;
  float* attf = ws + 2693632;
  float* attw = ws + 3659520;
  float* ctx  = ws + 3780256;
  float* AO   = ws + 4095648;
  _Float16* w1hi = (_Float16*)(ws + 4473760);
  _Float16* w1lo = (_Float16*)(ws + 4604832);
  // dead-region reuse:
  float* wsum = ws + 1048576;   // old qws region (dead after k3)
  float* Sv   = ws + 1088000;   // old kmat region (dead after k3, exact fit)
  float* Qp   = ws +  786432;   // old OWT region (dead after k6; 156800 fl <= 262144)
  float* out1 = (float*)d_out;
  float* out2 = out1 + 16056320;

  hipLaunchKernelGGL(k0_transpose, dim3(2048), dim3(256), 0, stream, ipw, outw, mw1, WT, OWT, w1hi, w1lo);
  hipLaunchKernelGGL(k1_q,   dim3(154), dim3(256), 0, stream, text, ipb, g1, b1, WT, qws);
  hipLaunchKernelGGL(k2_kv,  dim3(392), dim3(512), 0, stream, F, ipb, g1, b1, WT, kmat, vmat);
  hipLaunchKernelGGL(k3_attn,dim3(640), dim3(256), 0, stream, qws, kmat, attf);
  hipLaunchKernelGGL(k4_ctx, dim3(640), dim3(256), 0, stream, attf, vmat, ctx);
  hipLaunchKernelGGL(k5_attw,dim3(472), dim3(256), 0, stream, attf, attw, out2);
  hipLaunchKernelGGL(k6_ao,  dim3(154), dim3(512), 0, stream, ctx, OWT, outb, g2, b2, AO);
  hipLaunchKernelGGL(k6b_sv, dim3(200), dim3(512), 0, stream, AO, attw, Sv, wsum);
  hipLaunchKernelGGL(k7_mlp, dim3(3920),dim3(512), 0, stream, F, AO, attw, w1hi, w1lo, mb1, mlg, mlb, mw2, mb2, Sv, wsum, Qp);
  hipLaunchKernelGGL(k8_topk,dim3(1568),dim3(256), 0, stream, F, tmpl, Qp, out1);
}